// Round 6
// baseline (1874.645 us; speedup 1.0000x reference)
//
#include <hip/hip_runtime.h>
#include <cstdint>
#include <cstddef>

#define DIN 768
#define HD  256
#define LSEQ 512
#define IDIM 512

__device__ __forceinline__ float siluf(float v) { return v / (1.0f + __expf(-v)); }

// 8 cubic B-spline basis values, grid_size=5, order=3. Grid matches JAX exactly:
// grid[t] = (t-3)*0.4f - 1.0f, t=0..11 (arange(-3,9)*(2/5)-1 in f32).
__device__ __forceinline__ void bspline8(float x, float* bb) {
  float b[11];
#pragma unroll
  for (int t = 0; t < 11; ++t) {
    float g0 = (float)(t - 3) * 0.4f - 1.0f;
    float g1 = (float)(t - 2) * 0.4f - 1.0f;
    b[t] = (x >= g0 && x < g1) ? 1.0f : 0.0f;
  }
#pragma unroll
  for (int kk = 1; kk <= 3; ++kk) {
#pragma unroll
    for (int t = 0; t + kk < 11; ++t) {
      float gt   = (float)(t - 3) * 0.4f - 1.0f;
      float gtk  = (float)(t + kk - 3) * 0.4f - 1.0f;
      float gtk1 = (float)(t + kk - 2) * 0.4f - 1.0f;
      float gt1  = (float)(t - 2) * 0.4f - 1.0f;
      float left  = (x - gt) * (1.0f / (gtk - gt));
      float right = (gtk1 - x) * (1.0f / (gtk1 - gt1));
      b[t] = left * b[t] + right * b[t + 1];
    }
  }
#pragma unroll
  for (int j = 0; j < 8; ++j) bb[j] = b[j];
}

// ---- prep: pack kan1 weights as W9[d][o][9]: j=0..7 spline*ss, j=8 base weight.
// 72 contiguous floats per (d, 8-col group) -> wave-uniform s_load stream.
__global__ __launch_bounds__(256) void prep_w9_kernel(
    const float* __restrict__ bw, const float* __restrict__ sw, const float* __restrict__ ss,
    float* __restrict__ W9)
{
  int idx = blockIdx.x * 256 + threadIdx.x;   // 768*256
  int d = idx >> 8;
  int o = idx & 255;
  float sc = ss[(size_t)o * DIN + d];
  const float* sp = &sw[((size_t)o * DIN + d) * 8];
  float* dst = &W9[(size_t)idx * 9];
#pragma unroll
  for (int j = 0; j < 8; ++j) dst[j] = sp[j] * sc;
  dst[8] = bw[(size_t)o * DIN + d];
}

// ---- KAN-1 (spline + silu base), raw output (LN is a separate pass: a block
// covers only 32 of 256 cols, so row statistics CANNOT be computed here).
// lanes = rows. Block: 128 rows x 32 cols, 512 threads = 8 waves.
// Wave w: rg=w>>2 (row half), cw=w&3 (8-col group). Each thread: 1 row, 8 cols.
// Weight pointer is wave-uniform (readfirstlane) -> scalar loads through
// constant cache: zero VALU / zero per-lane VMEM for weights.
// Basis per (row,d) computed once by the whole block, shared via LDS.
__global__ __launch_bounds__(512) void kan1_kernel(
    const float* __restrict__ x, const float* __restrict__ W9, float* __restrict__ hraw)
{
  const int DCH = 4;
  __shared__ float4 basA[DCH][128];
  __shared__ float4 basB[DCH][128];
  __shared__ float  basS[DCH][128];
  int tid = threadIdx.x;
  int lane = tid & 63;
  int w = tid >> 6;
  int rg = w >> 2;                 // 0/1
  int cw = w & 3;                  // 8-col group within block
  int r0 = blockIdx.x * 128;
  int c0 = blockIdx.y * 32 + cw * 8;
  int sc0 = __builtin_amdgcn_readfirstlane(c0);
  const float* wbase = W9 + (size_t)sc0 * 9;   // wave-uniform
  int srow = tid >> 2;             // staging row 0..127
  int sdd = tid & 3;               // staging d within chunk
  int myrow = rg * 64 + lane;

  float acc[8];
#pragma unroll
  for (int c = 0; c < 8; ++c) acc[c] = 0.0f;

  float xcur = x[(size_t)(r0 + srow) * DIN + sdd];

#pragma unroll 1
  for (int d0 = 0; d0 < DIN; d0 += DCH) {
    __syncthreads();               // previous chunk's basis fully consumed
    {
      float bb[8];
      bspline8(xcur, bb);
      basA[sdd][srow] = make_float4(bb[0], bb[1], bb[2], bb[3]);
      basB[sdd][srow] = make_float4(bb[4], bb[5], bb[6], bb[7]);
      basS[sdd][srow] = siluf(xcur);
      if (d0 + DCH < DIN) xcur = x[(size_t)(r0 + srow) * DIN + d0 + DCH + sdd];
    }
    __syncthreads();               // basis visible

    const float* wd = wbase + (size_t)(d0) * (HD * 9);
#pragma unroll
    for (int dd = 0; dd < DCH; ++dd) {
      float4 b0 = basA[dd][myrow];
      float4 b1 = basB[dd][myrow];
      float s  = basS[dd][myrow];
      const float* wc = wd + dd * (HD * 9);   // wave-uniform, 72 contiguous floats
#pragma unroll
      for (int c = 0; c < 8; ++c) {
        const float* p = wc + c * 9;
        acc[c] += s * p[8]
                + b0.x * p[0] + b0.y * p[1] + b0.z * p[2] + b0.w * p[3]
                + b1.x * p[4] + b1.y * p[5] + b1.z * p[6] + b1.w * p[7];
      }
    }
  }

  float* hp = &hraw[(size_t)(r0 + myrow) * HD + c0];
  *(float4*)hp = make_float4(acc[0], acc[1], acc[2], acc[3]);
  *(float4*)(hp + 4) = make_float4(acc[4], acc[5], acc[6], acc[7]);
}

// ---- LayerNorm: one block per row of 256 (full-H statistics)
__global__ __launch_bounds__(256) void layernorm_kernel(
    const float* __restrict__ in, const float* __restrict__ g, const float* __restrict__ b,
    float* __restrict__ out)
{
  __shared__ float pS[4], pQ[4];
  int row = blockIdx.x, tid = threadIdx.x;
  float v = in[(size_t)row * 256 + tid];
  float s = v, q = v * v;
#pragma unroll
  for (int off = 1; off < 64; off <<= 1) { s += __shfl_xor(s, off); q += __shfl_xor(q, off); }
  if ((tid & 63) == 0) { pS[tid >> 6] = s; pQ[tid >> 6] = q; }
  __syncthreads();
  float S = pS[0] + pS[1] + pS[2] + pS[3];
  float Q = pQ[0] + pQ[1] + pQ[2] + pQ[3];
  float m = S * (1.0f / 256.0f);
  float var = Q * (1.0f / 256.0f) - m * m;
  float rs = rsqrtf(var + 1e-5f);
  out[(size_t)row * 256 + tid] = (v - m) * rs * g[tid] + b[tid];
}

// ---- RMSNorm: one block per row of 256
__global__ __launch_bounds__(256) void rmsnorm_kernel(
    const float* __restrict__ in, const float* __restrict__ w, float* __restrict__ out)
{
  __shared__ float p[4];
  int row = blockIdx.x, tid = threadIdx.x;
  float v = in[(size_t)row * 256 + tid];
  float q = v * v;
#pragma unroll
  for (int off = 1; off < 64; off <<= 1) q += __shfl_xor(q, off);
  if ((tid & 63) == 0) p[tid >> 6] = q;
  __syncthreads();
  float s = p[0] + p[1] + p[2] + p[3];
  float rstd = rsqrtf(s * (1.0f / 256.0f) + 1e-5f);
  out[(size_t)row * 256 + tid] = w[tid] * v * rstd;
}

// ---- fp32 GEMM 128x(NH*64)x16, 256 threads, 8x(NH*4) per thread.
template<int NH, int EP>
__global__ __launch_bounds__(256) void gemm128(
    const float* __restrict__ A, const float* __restrict__ W, float* __restrict__ C,
    int N, int K)
{
  __shared__ float As[16][132];
  __shared__ float Wsm[16][NH * 64 + 4];
  int tid = threadIdx.x;
  int bx = blockIdx.x, by = blockIdx.y;
  int tx = tid & 15, ty = tid >> 4;
  int lr = tid >> 1;
  int lk = (tid & 1) << 3;
  int wr = (NH == 2) ? lr : (tid >> 2);
  int wk = (NH == 2) ? lk : ((tid & 3) << 2);
  const float* Ap = A + (size_t)(bx * 128 + lr) * K + lk;
  const float* Wp = W + (size_t)(by * (NH * 64) + wr) * K + wk;
  float acc[8][NH * 4];
#pragma unroll
  for (int i = 0; i < 8; ++i)
#pragma unroll
    for (int j = 0; j < NH * 4; ++j) acc[i][j] = 0.0f;

#pragma unroll 1
  for (int k0 = 0; k0 < K; k0 += 16) {
    float4 av0 = *(const float4*)(Ap + k0);
    float4 av1 = *(const float4*)(Ap + k0 + 4);
    float4 wv0 = *(const float4*)(Wp + k0);
    float4 wv1;
    if constexpr (NH == 2) wv1 = *(const float4*)(Wp + k0 + 4);
    __syncthreads();
    As[lk + 0][lr] = av0.x; As[lk + 1][lr] = av0.y; As[lk + 2][lr] = av0.z; As[lk + 3][lr] = av0.w;
    As[lk + 4][lr] = av1.x; As[lk + 5][lr] = av1.y; As[lk + 6][lr] = av1.z; As[lk + 7][lr] = av1.w;
    Wsm[wk + 0][wr] = wv0.x; Wsm[wk + 1][wr] = wv0.y; Wsm[wk + 2][wr] = wv0.z; Wsm[wk + 3][wr] = wv0.w;
    if constexpr (NH == 2) {
      Wsm[wk + 4][wr] = wv1.x; Wsm[wk + 5][wr] = wv1.y; Wsm[wk + 6][wr] = wv1.z; Wsm[wk + 7][wr] = wv1.w;
    }
    __syncthreads();
#pragma unroll
    for (int kk = 0; kk < 16; ++kk) {
      float4 a0 = *(const float4*)&As[kk][ty * 4];
      float4 a1 = *(const float4*)&As[kk][64 + ty * 4];
      float af[8] = {a0.x, a0.y, a0.z, a0.w, a1.x, a1.y, a1.z, a1.w};
      float wf[8];
      float4 b0 = *(const float4*)&Wsm[kk][tx * 4];
      wf[0] = b0.x; wf[1] = b0.y; wf[2] = b0.z; wf[3] = b0.w;
      if constexpr (NH == 2) {
        float4 b1 = *(const float4*)&Wsm[kk][64 + tx * 4];
        wf[4] = b1.x; wf[5] = b1.y; wf[6] = b1.z; wf[7] = b1.w;
      }
#pragma unroll
      for (int i = 0; i < 8; ++i)
#pragma unroll
        for (int j = 0; j < NH * 4; ++j)
          acc[i][j] += af[i] * wf[j];
    }
  }
#pragma unroll
  for (int i = 0; i < 8; ++i) {
    int rloc = (i < 4) ? (ty * 4 + i) : (60 + ty * 4 + i);
    float* cp = C + (size_t)(bx * 128 + rloc) * N + by * (NH * 64) + tx * 4;
    float4 v0 = make_float4(acc[i][0], acc[i][1], acc[i][2], acc[i][3]);
    if constexpr (EP == 1) {
      float4 o = *(const float4*)cp;
      v0 = make_float4(o.x + v0.x, o.y + v0.y, o.z + v0.z, o.w + v0.w);
    }
    *(float4*)cp = v0;
    if constexpr (NH == 2) {
      float* cp1 = cp + 64;
      float4 v1 = make_float4(acc[i][4], acc[i][5], acc[i][6], acc[i][7]);
      if constexpr (EP == 1) {
        float4 o = *(const float4*)cp1;
        v1 = make_float4(o.x + v1.x, o.y + v1.y, o.z + v1.z, o.w + v1.w);
      }
      *(float4*)cp1 = v1;
    }
  }
}

// ---- fp32 GEMM 64x64x16, 4x4/thread — kept for N=48 (x_proj)
template<int EP>
__global__ __launch_bounds__(256) void gemm_nt(
    const float* __restrict__ A, const float* __restrict__ W, float* __restrict__ C,
    int M, int N, int K)
{
  __shared__ float As[16][68];
  __shared__ float Wsm[16][68];
  int tid = threadIdx.x;
  int bx = blockIdx.x, by = blockIdx.y;
  int tx = tid & 15, ty = tid >> 4;
  int lr = tid >> 2;
  int lk = (tid & 3) << 2;
  const float* Ap = A + (size_t)(bx * 64 + lr) * K + lk;
  int wrow = by * 64 + lr;
  bool wv = wrow < N;
  const float* Wp = W + (size_t)(wv ? wrow : 0) * K + lk;
  float acc[4][4];
#pragma unroll
  for (int i = 0; i < 4; ++i)
#pragma unroll
    for (int j = 0; j < 4; ++j) acc[i][j] = 0.0f;

#pragma unroll 1
  for (int k0 = 0; k0 < K; k0 += 16) {
    float4 av = *(const float4*)(Ap + k0);
    float4 wvv = wv ? *(const float4*)(Wp + k0) : make_float4(0.f, 0.f, 0.f, 0.f);
    __syncthreads();
    As[lk + 0][lr] = av.x; As[lk + 1][lr] = av.y; As[lk + 2][lr] = av.z; As[lk + 3][lr] = av.w;
    Wsm[lk + 0][lr] = wvv.x; Wsm[lk + 1][lr] = wvv.y; Wsm[lk + 2][lr] = wvv.z; Wsm[lk + 3][lr] = wvv.w;
    __syncthreads();
#pragma unroll
    for (int kk = 0; kk < 16; ++kk) {
      float4 a = *(const float4*)&As[kk][ty * 4];
      float4 b = *(const float4*)&Wsm[kk][tx * 4];
      acc[0][0] += a.x * b.x; acc[0][1] += a.x * b.y; acc[0][2] += a.x * b.z; acc[0][3] += a.x * b.w;
      acc[1][0] += a.y * b.x; acc[1][1] += a.y * b.y; acc[1][2] += a.y * b.z; acc[1][3] += a.y * b.w;
      acc[2][0] += a.z * b.x; acc[2][1] += a.z * b.y; acc[2][2] += a.z * b.z; acc[2][3] += a.z * b.w;
      acc[3][0] += a.w * b.x; acc[3][1] += a.w * b.y; acc[3][2] += a.w * b.z; acc[3][3] += a.w * b.w;
    }
  }
#pragma unroll
  for (int i = 0; i < 4; ++i) {
    int row = bx * 64 + ty * 4 + i;
    int col = by * 64 + tx * 4;
    float* cp = C + (size_t)row * N + col;
    if (col + 3 < N) {
      float4 o;
      if (EP == 1) {
        float4 old = *(const float4*)cp;
        o = make_float4(old.x + acc[i][0], old.y + acc[i][1], old.z + acc[i][2], old.w + acc[i][3]);
      } else {
        o = make_float4(acc[i][0], acc[i][1], acc[i][2], acc[i][3]);
      }
      *(float4*)cp = o;
    } else {
#pragma unroll
      for (int j = 0; j < 4; ++j) if (col + j < N) {
        float v = acc[i][j];
        if (EP == 1) v += cp[j];
        cp[j] = v;
      }
    }
  }
}

// ---- causal depthwise conv (K=4) + bias + SiLU, reading u-half of proj
__global__ __launch_bounds__(256) void conv_silu_kernel(
    const float* __restrict__ proj, const float* __restrict__ cw, const float* __restrict__ cb,
    float* __restrict__ u2)
{
  int idx = blockIdx.x * 256 + threadIdx.x;   // B*L*I = 4194304
  int i = idx & 511;
  int l = (idx >> 9) & 511;
  int bl = idx >> 9;
  const float* p = proj + (size_t)bl * 1024 + i;
  float4 w = *(const float4*)&cw[i * 4];
  float s = cb[i];
  s += (l >= 3) ? p[-3 * 1024] * w.x : 0.0f;
  s += (l >= 2) ? p[-2 * 1024] * w.y : 0.0f;
  s += (l >= 1) ? p[-1 * 1024] * w.z : 0.0f;
  s += p[0] * w.w;
  u2[idx] = siluf(s);
}

// ---- selective scan, dt-GEMM folded in. grid (I/64, B), 256 thr.
__global__ __launch_bounds__(256) void scan_kernel(
    const float* __restrict__ ssm, float* __restrict__ u2, const float* __restrict__ proj,
    const float* __restrict__ dtw, const float* __restrict__ dtb, const float* __restrict__ alog,
    const float* __restrict__ Dp)
{
  const int CL = 64;
  __shared__ float sbuf[CL * 48];
  __shared__ float ubuf[CL][64];
  __shared__ float gbuf[CL][64];
  int tid = threadIdx.x;
  int il = tid >> 2, ns = tid & 3;
  int i0 = blockIdx.x * 64;
  int i = i0 + il;
  int b = blockIdx.y;
  float A4[4], wr4[4];
#pragma unroll
  for (int nn = 0; nn < 4; ++nn) {
    A4[nn] = -__expf(alog[i * 16 + ns * 4 + nn]);
    wr4[nn] = dtw[i * 16 + ns * 4 + nn];
  }
  float dtbi = dtb[i], Di = Dp[i];
  float st0 = 0.f, st1 = 0.f, st2 = 0.f, st3 = 0.f;
  size_t rowL = (size_t)b * 512;

#pragma unroll 1
  for (int c = 0; c < 512; c += CL) {
    __syncthreads();
    {
      const float* src = ssm + (rowL + c) * 48;
      for (int t = tid; t < CL * 48; t += 256) sbuf[t] = src[t];
    }
    for (int t = tid; t < CL * 64; t += 256) {
      int lc = t >> 6, ci = t & 63;
      ubuf[lc][ci] = u2[(rowL + c + lc) * 512 + i0 + ci];
      gbuf[lc][ci] = proj[(rowL + c + lc) * 1024 + 512 + i0 + ci];
    }
    __syncthreads();
    for (int ll = 0; ll < CL; ++ll) {
      const float* row = &sbuf[ll * 48];
      float4 dtr = *(const float4*)(row + ns * 4);
      float pdt = dtr.x * wr4[0] + dtr.y * wr4[1] + dtr.z * wr4[2] + dtr.w * wr4[3];
      pdt += __shfl_xor(pdt, 1);
      pdt += __shfl_xor(pdt, 2);
      pdt += dtbi;
      float dtv = (pdt > 20.0f) ? pdt : __logf(1.0f + __expf(pdt));
      float u = ubuf[ll][il];
      float dtu = dtv * u;
      float4 Bv = *(const float4*)(row + 16 + ns * 4);
      float4 Cv = *(const float4*)(row + 32 + ns * 4);
      st0 = st0 * __expf(dtv * A4[0]) + dtu * Bv.x;
      st1 = st1 * __expf(dtv * A4[1]) + dtu * Bv.y;
      st2 = st2 * __expf(dtv * A4[2]) + dtu * Bv.z;
      st3 = st3 * __expf(dtv * A4[3]) + dtu * Bv.w;
      float yp = st0 * Cv.x + st1 * Cv.y + st2 * Cv.z + st3 * Cv.w;
      yp += __shfl_xor(yp, 1);
      yp += __shfl_xor(yp, 2);
      if (ns == 0) {
        float gt = gbuf[ll][il];
        ubuf[ll][il] = (yp + u * Di) * siluf(gt);
      }
    }
    __syncthreads();
    for (int t = tid; t < CL * 64; t += 256) {
      int lc = t >> 6, ci = t & 63;
      u2[(rowL + c + lc) * 512 + i0 + ci] = ubuf[lc][ci];
    }
  }
}

// ---- mean/max pool over L after final rmsnorm; writes emb into d_out+32
__global__ __launch_bounds__(64) void pool_kernel(const float* __restrict__ hn, float* __restrict__ outp)
{
  int c = blockIdx.x * 64 + threadIdx.x;
  int b = blockIdx.y;
  float s = 0.0f, mx = -3.4e38f;
  for (int l = 0; l < 512; ++l) {
    float v = hn[((size_t)b * 512 + l) * 256 + c];
    s += v;
    mx = fmaxf(mx, v);
  }
  outp[32 + b * 512 + c] = s * (1.0f / 512.0f);
  outp[32 + b * 512 + 256 + c] = mx;
}

// ---- KAN-2 head: (16, 512) -> (16, 2). One block per b.
__global__ __launch_bounds__(256) void kan2_kernel(
    const float* __restrict__ outp, const float* __restrict__ bw2, const float* __restrict__ sw2,
    const float* __restrict__ ss2, float* __restrict__ logits)
{
  __shared__ float r0[256], r1[256];
  int b = blockIdx.x, tid = threadIdx.x;
  float a0 = 0.0f, a1 = 0.0f;
#pragma unroll
  for (int dd = 0; dd < 2; ++dd) {
    int d = tid + dd * 256;
    float e = outp[32 + b * 512 + d];
    float bb[8];
    bspline8(e, bb);
    float sl = siluf(e);
    {
      float sc = ss2[d];
      const float* sp = &sw2[(size_t)d * 8];
      float t = sl * bw2[d];
      t += (bb[0] * sp[0] + bb[1] * sp[1] + bb[2] * sp[2] + bb[3] * sp[3]
          + bb[4] * sp[4] + bb[5] * sp[5] + bb[6] * sp[6] + bb[7] * sp[7]) * sc;
      a0 += t;
    }
    {
      float sc = ss2[512 + d];
      const float* sp = &sw2[(size_t)(512 + d) * 8];
      float t = sl * bw2[512 + d];
      t += (bb[0] * sp[0] + bb[1] * sp[1] + bb[2] * sp[2] + bb[3] * sp[3]
          + bb[4] * sp[4] + bb[5] * sp[5] + bb[6] * sp[6] + bb[7] * sp[7]) * sc;
      a1 += t;
    }
  }
  r0[tid] = a0; r1[tid] = a1;
  __syncthreads();
  for (int s = 128; s > 0; s >>= 1) {
    if (tid < s) { r0[tid] += r0[tid + s]; r1[tid] += r1[tid + s]; }
    __syncthreads();
  }
  if (tid == 0) { logits[b * 2 + 0] = r0[0]; logits[b * 2 + 1] = r1[0]; }
}

extern "C" void kernel_launch(void* const* d_in, const int* in_sizes, int n_in,
                              void* d_out, int out_size, void* d_ws, size_t ws_size,
                              hipStream_t stream)
{
  const float* x     = (const float*)d_in[0];
  const float* bw1   = (const float*)d_in[1];
  const float* sw1   = (const float*)d_in[2];
  const float* ss1   = (const float*)d_in[3];
  const float* lng   = (const float*)d_in[4];
  const float* lnb   = (const float*)d_in[5];
  const float* normw = (const float*)d_in[6];
  const float* ipw   = (const float*)d_in[7];
  const float* cw    = (const float*)d_in[8];
  const float* cb    = (const float*)d_in[9];
  const float* xpw   = (const float*)d_in[10];
  const float* dtw   = (const float*)d_in[11];
  const float* dtb   = (const float*)d_in[12];
  const float* alog  = (const float*)d_in[13];
  const float* Dp    = (const float*)d_in[14];
  const float* opw   = (const float*)d_in[15];
  const float* nfw   = (const float*)d_in[16];
  const float* bw2   = (const float*)d_in[17];
  const float* sw2   = (const float*)d_in[18];
  const float* ss2   = (const float*)d_in[19];
  float* out = (float*)d_out;

  float* ws   = (float*)d_ws;
  float* W9   = ws;                       // 768*256*9 = 1769472
  float* h    = W9 + 1769472;             // 2097152
  float* xn   = h + 2097152;              // 2097152
  float* proj = xn + 2097152;             // 8388608
  float* u2   = proj + 8388608;           // 4194304
  float* ssmb = u2 + 4194304;             // 393216  -> total ~76 MB

  prep_w9_kernel<<<768, 256, 0, stream>>>(bw1, sw1, ss1, W9);
  kan1_kernel<<<dim3(64, 8), 512, 0, stream>>>(x, W9, xn);       // raw -> xn
  layernorm_kernel<<<8192, 256, 0, stream>>>(xn, lng, lnb, h);   // h = LN(xn)

  for (int l = 0; l < 2; ++l) {
    rmsnorm_kernel<<<8192, 256, 0, stream>>>(h, normw + l * 256, xn);
    // in_proj: (8192,256)@(1024,256)^T -> (8192,1024)
    gemm128<2, 0><<<dim3(64, 8), 256, 0, stream>>>(xn, ipw + (size_t)l * 262144, proj, 1024, 256);
    conv_silu_kernel<<<16384, 256, 0, stream>>>(proj, cw + l * 2048, cb + l * 512, u2);
    // x_proj: (8192,512)@(48,512)^T -> (8192,48)
    gemm_nt<0><<<dim3(128, 1), 256, 0, stream>>>(u2, xpw + (size_t)l * 24576, ssmb, 8192, 48, 512);
    scan_kernel<<<dim3(8, 16), 256, 0, stream>>>(ssmb, u2, proj,
                                                 dtw + l * 8192, dtb + l * 512,
                                                 alog + l * 8192, Dp + l * 512);
    // out_proj (+residual): (8192,512)@(256,512)^T += h
    gemm128<1, 1><<<dim3(64, 4), 256, 0, stream>>>(u2, opw + (size_t)l * 131072, h, 256, 512);
  }

  rmsnorm_kernel<<<8192, 256, 0, stream>>>(h, nfw, xn);
  pool_kernel<<<dim3(4, 16), 64, 0, stream>>>(xn, out);
  kan2_kernel<<<16, 256, 0, stream>>>(out, bw2, sw2, ss2, out);
}

// Round 7
// 1100.093 us; speedup vs baseline: 1.7041x; 1.7041x over previous
//
#include <hip/hip_runtime.h>
#include <cstdint>
#include <cstddef>

#define DIN 768
#define HD  256
#define LSEQ 512
#define IDIM 512

typedef __attribute__((ext_vector_type(8))) short bf16x8;
typedef __attribute__((ext_vector_type(4))) float f32x4;

__device__ __forceinline__ float siluf(float v) { return v / (1.0f + __expf(-v)); }

__device__ __forceinline__ ushort bf16rne(float v) {
  uint u = __float_as_uint(v);
  uint r = u + 0x7fffu + ((u >> 16) & 1u);
  return (ushort)(r >> 16);
}

// 8 cubic B-spline basis values (recursion form) — still used by kan2 (tiny).
__device__ __forceinline__ void bspline8(float x, float* bb) {
  float b[11];
#pragma unroll
  for (int t = 0; t < 11; ++t) {
    float g0 = (float)(t - 3) * 0.4f - 1.0f;
    float g1 = (float)(t - 2) * 0.4f - 1.0f;
    b[t] = (x >= g0 && x < g1) ? 1.0f : 0.0f;
  }
#pragma unroll
  for (int kk = 1; kk <= 3; ++kk) {
#pragma unroll
    for (int t = 0; t + kk < 11; ++t) {
      float gt   = (float)(t - 3) * 0.4f - 1.0f;
      float gtk  = (float)(t + kk - 3) * 0.4f - 1.0f;
      float gtk1 = (float)(t + kk - 2) * 0.4f - 1.0f;
      float gt1  = (float)(t - 2) * 0.4f - 1.0f;
      float left  = (x - gt) * (1.0f / (gtk - gt));
      float right = (gtk1 - x) * (1.0f / (gtk1 - gt1));
      b[t] = left * b[t] + right * b[t + 1];
    }
  }
#pragma unroll
  for (int j = 0; j < 8; ++j) bb[j] = b[j];
}

// ---- transpose x (8192x768) -> xT (768x8192), LDS 64x64 tiles
__global__ __launch_bounds__(256) void prep_xT_kernel(
    const float* __restrict__ x, float* __restrict__ xT)
{
  __shared__ float tile[64][65];
  int t = threadIdx.x;
  int rb = t >> 6, c = t & 63;
  int n0 = blockIdx.x * 64, d0 = blockIdx.y * 64;
#pragma unroll
  for (int p = 0; p < 16; ++p) {
    int r = p * 4 + rb;
    tile[r][c] = x[(size_t)(n0 + r) * DIN + d0 + c];
  }
  __syncthreads();
#pragma unroll
  for (int p = 0; p < 16; ++p) {
    int r = p * 4 + rb;
    xT[(size_t)(d0 + r) * 8192 + n0 + c] = tile[c][r];
  }
}

// ---- pack kan1 weights bf16: WT[o][k], k<6144: spline(o,d=k/8,j=k%8)*ss; k>=6144: base bw[o][k-6144]
__global__ __launch_bounds__(256) void prep_WT_kernel(
    const float* __restrict__ bw, const float* __restrict__ sw, const float* __restrict__ ss,
    ushort* __restrict__ WT)
{
  int k = blockIdx.x * 256 + threadIdx.x;   // 0..6911 (27 blocks)
  int o = blockIdx.y;
  float v;
  if (k < 6144) {
    int d = k >> 3, j = k & 7;
    v = sw[((size_t)o * DIN + d) * 8 + j] * ss[(size_t)o * DIN + d];
  } else {
    v = bw[(size_t)o * DIN + (k - 6144)];
  }
  WT[(size_t)o * 6912 + k] = bf16rne(v);
}

// ---- KAN-1 as bf16 MFMA GEMM: C[8192,256] = A[8192,6912] @ WT^T.
// A (fused in staging): k<6144 -> closed-form cubic B-spline basis of xT[d][n];
// k>=6144 -> silu(x). BM=64, BN=128, 256 thr (4 waves), grid(128,2)=256 blocks.
// Wave w: cols w*32..+32 (2 N-tiles), rows 0..63 (4 M-tiles). 16x16x32 bf16 MFMA.
// LDS stride 40 ushort (80B = 20 words -> 2-way bank alias = free).
__global__ __launch_bounds__(256) void kan1_mfma_kernel(
    const float* __restrict__ xT, const ushort* __restrict__ WT, float* __restrict__ xn)
{
  __shared__ __align__(16) ushort A_lds[64][40];
  __shared__ __align__(16) ushort B_lds[128][40];
  int tid = threadIdx.x;
  int l = tid & 63;
  int w = tid >> 6;
  int n0 = blockIdx.x * 64;
  int c0 = blockIdx.y * 128;

  f32x4 acc[4][2];
#pragma unroll
  for (int t = 0; t < 4; ++t)
#pragma unroll
    for (int ct = 0; ct < 2; ++ct)
#pragma unroll
      for (int i = 0; i < 4; ++i) acc[t][ct][i] = 0.0f;

  int ar = tid & 63;        // A staging row
  int aq = tid >> 6;        // A staging k-quarter (8 k's each)
  int bc = tid & 127;       // B staging col
  int bh = tid >> 7;        // B staging k-half (16 k's each)
  const ushort* wrow = &WT[(size_t)(c0 + bc) * 6912];

#pragma unroll 1
  for (int ks = 0; ks < 216; ++ks) {
    int k0 = ks * 32;
    __syncthreads();
    // ---- B staging: 128 cols x 32 k
    {
      const float4* src = (const float4*)(wrow + k0 + bh * 16);
      float4 v0 = src[0], v1 = src[1];
      float4* dst = (float4*)&B_lds[bc][bh * 16];
      dst[0] = v0; dst[1] = v1;
    }
    // ---- A staging: 64 rows x 32 k
    if (k0 < 6144) {
      // spline segment: this thread covers (row ar, d = k0/8 + aq), j=0..7
      int d = (k0 >> 3) + aq;
      float xv = xT[(size_t)d * 8192 + n0 + ar];
      float sxp = (xv + 2.2f) * 2.5f;        // knot-unit position; cell m
      float mf = floorf(sxp);
      int m = (int)mf;
      float u = sxp - mf;                    // local coord in [0,1)
      float uu = u * u, uuu = uu * u;
      float vmask = (m >= 0 && m <= 10) ? (1.0f / 6.0f) : 0.0f;  // outside grid -> all-zero basis
      float p0 = uuu * vmask;                                     // j = m   (rising edge)
      float p1 = (-3.f * uuu + 3.f * uu + 3.f * u + 1.f) * vmask; // j = m-1
      float p2 = (3.f * uuu - 6.f * uu + 4.f) * vmask;            // j = m-2
      float om = 1.f - u;
      float p3 = om * om * om * vmask;                            // j = m-3 (falling edge)
      ushort* arow = &A_lds[ar][aq * 8];
      *(float4*)arow = make_float4(0.f, 0.f, 0.f, 0.f);
      if (m >= 0 && m <= 7)  arow[m]     = bf16rne(p0);
      if (m >= 1 && m <= 8)  arow[m - 1] = bf16rne(p1);
      if (m >= 2 && m <= 9)  arow[m - 2] = bf16rne(p2);
      if (m >= 3 && m <= 10) arow[m - 3] = bf16rne(p3);
    } else {
      // base segment: silu(x) for 8 consecutive d
      int db = (k0 - 6144) + aq * 8;
      uint pk[4];
#pragma unroll
      for (int i = 0; i < 4; ++i) {
        float x0 = xT[(size_t)(db + 2 * i) * 8192 + n0 + ar];
        float x1 = xT[(size_t)(db + 2 * i + 1) * 8192 + n0 + ar];
        pk[i] = (uint)bf16rne(siluf(x0)) | ((uint)bf16rne(siluf(x1)) << 16);
      }
      uint4* dst = (uint4*)&A_lds[ar][aq * 8];
      *dst = make_uint4(pk[0], pk[1], pk[2], pk[3]);
    }
    __syncthreads();
    // ---- fragments + MFMA
    bf16x8 bfr0 = *(bf16x8*)&B_lds[w * 32 + (l & 15)][(l >> 4) * 8];
    bf16x8 bfr1 = *(bf16x8*)&B_lds[w * 32 + 16 + (l & 15)][(l >> 4) * 8];
#pragma unroll
    for (int t = 0; t < 4; ++t) {
      bf16x8 afr = *(bf16x8*)&A_lds[t * 16 + (l & 15)][(l >> 4) * 8];
      acc[t][0] = __builtin_amdgcn_mfma_f32_16x16x32_bf16(afr, bfr0, acc[t][0], 0, 0, 0);
      acc[t][1] = __builtin_amdgcn_mfma_f32_16x16x32_bf16(afr, bfr1, acc[t][1], 0, 0, 0);
    }
  }
  // ---- epilogue: C/D layout col=lane&15, row=(lane>>4)*4+reg (m89-verified)
#pragma unroll
  for (int t = 0; t < 4; ++t)
#pragma unroll
    for (int ct = 0; ct < 2; ++ct)
#pragma unroll
      for (int i = 0; i < 4; ++i) {
        int row = n0 + t * 16 + (l >> 4) * 4 + i;
        int col = c0 + w * 32 + ct * 16 + (l & 15);
        xn[(size_t)row * HD + col] = acc[t][ct][i];
      }
}

// ---- LayerNorm: one block per row of 256 (full-H statistics)
__global__ __launch_bounds__(256) void layernorm_kernel(
    const float* __restrict__ in, const float* __restrict__ g, const float* __restrict__ b,
    float* __restrict__ out)
{
  __shared__ float pS[4], pQ[4];
  int row = blockIdx.x, tid = threadIdx.x;
  float v = in[(size_t)row * 256 + tid];
  float s = v, q = v * v;
#pragma unroll
  for (int off = 1; off < 64; off <<= 1) { s += __shfl_xor(s, off); q += __shfl_xor(q, off); }
  if ((tid & 63) == 0) { pS[tid >> 6] = s; pQ[tid >> 6] = q; }
  __syncthreads();
  float S = pS[0] + pS[1] + pS[2] + pS[3];
  float Q = pQ[0] + pQ[1] + pQ[2] + pQ[3];
  float m = S * (1.0f / 256.0f);
  float var = Q * (1.0f / 256.0f) - m * m;
  float rs = rsqrtf(var + 1e-5f);
  out[(size_t)row * 256 + tid] = (v - m) * rs * g[tid] + b[tid];
}

// ---- RMSNorm: one block per row of 256
__global__ __launch_bounds__(256) void rmsnorm_kernel(
    const float* __restrict__ in, const float* __restrict__ w, float* __restrict__ out)
{
  __shared__ float p[4];
  int row = blockIdx.x, tid = threadIdx.x;
  float v = in[(size_t)row * 256 + tid];
  float q = v * v;
#pragma unroll
  for (int off = 1; off < 64; off <<= 1) q += __shfl_xor(q, off);
  if ((tid & 63) == 0) p[tid >> 6] = q;
  __syncthreads();
  float s = p[0] + p[1] + p[2] + p[3];
  float rstd = rsqrtf(s * (1.0f / 256.0f) + 1e-5f);
  out[(size_t)row * 256 + tid] = w[tid] * v * rstd;
}

// ---- fp32 GEMM 128x(NH*64)x16, 256 threads, 8x(NH*4) per thread.
template<int NH, int EP>
__global__ __launch_bounds__(256) void gemm128(
    const float* __restrict__ A, const float* __restrict__ W, float* __restrict__ C,
    int N, int K)
{
  __shared__ float As[16][132];
  __shared__ float Wsm[16][NH * 64 + 4];
  int tid = threadIdx.x;
  int bx = blockIdx.x, by = blockIdx.y;
  int tx = tid & 15, ty = tid >> 4;
  int lr = tid >> 1;
  int lk = (tid & 1) << 3;
  int wr = (NH == 2) ? lr : (tid >> 2);
  int wk = (NH == 2) ? lk : ((tid & 3) << 2);
  const float* Ap = A + (size_t)(bx * 128 + lr) * K + lk;
  const float* Wp = W + (size_t)(by * (NH * 64) + wr) * K + wk;
  float acc[8][NH * 4];
#pragma unroll
  for (int i = 0; i < 8; ++i)
#pragma unroll
    for (int j = 0; j < NH * 4; ++j) acc[i][j] = 0.0f;

#pragma unroll 1
  for (int k0 = 0; k0 < K; k0 += 16) {
    float4 av0 = *(const float4*)(Ap + k0);
    float4 av1 = *(const float4*)(Ap + k0 + 4);
    float4 wv0 = *(const float4*)(Wp + k0);
    float4 wv1;
    if constexpr (NH == 2) wv1 = *(const float4*)(Wp + k0 + 4);
    __syncthreads();
    As[lk + 0][lr] = av0.x; As[lk + 1][lr] = av0.y; As[lk + 2][lr] = av0.z; As[lk + 3][lr] = av0.w;
    As[lk + 4][lr] = av1.x; As[lk + 5][lr] = av1.y; As[lk + 6][lr] = av1.z; As[lk + 7][lr] = av1.w;
    Wsm[wk + 0][wr] = wv0.x; Wsm[wk + 1][wr] = wv0.y; Wsm[wk + 2][wr] = wv0.z; Wsm[wk + 3][wr] = wv0.w;
    if constexpr (NH == 2) {
      Wsm[wk + 4][wr] = wv1.x; Wsm[wk + 5][wr] = wv1.y; Wsm[wk + 6][wr] = wv1.z; Wsm[wk + 7][wr] = wv1.w;
    }
    __syncthreads();
#pragma unroll
    for (int kk = 0; kk < 16; ++kk) {
      float4 a0 = *(const float4*)&As[kk][ty * 4];
      float4 a1 = *(const float4*)&As[kk][64 + ty * 4];
      float af[8] = {a0.x, a0.y, a0.z, a0.w, a1.x, a1.y, a1.z, a1.w};
      float wf[8];
      float4 b0 = *(const float4*)&Wsm[kk][tx * 4];
      wf[0] = b0.x; wf[1] = b0.y; wf[2] = b0.z; wf[3] = b0.w;
      if constexpr (NH == 2) {
        float4 b1 = *(const float4*)&Wsm[kk][64 + tx * 4];
        wf[4] = b1.x; wf[5] = b1.y; wf[6] = b1.z; wf[7] = b1.w;
      }
#pragma unroll
      for (int i = 0; i < 8; ++i)
#pragma unroll
        for (int j = 0; j < NH * 4; ++j)
          acc[i][j] += af[i] * wf[j];
    }
  }
#pragma unroll
  for (int i = 0; i < 8; ++i) {
    int rloc = (i < 4) ? (ty * 4 + i) : (60 + ty * 4 + i);
    float* cp = C + (size_t)(bx * 128 + rloc) * N + by * (NH * 64) + tx * 4;
    float4 v0 = make_float4(acc[i][0], acc[i][1], acc[i][2], acc[i][3]);
    if constexpr (EP == 1) {
      float4 o = *(const float4*)cp;
      v0 = make_float4(o.x + v0.x, o.y + v0.y, o.z + v0.z, o.w + v0.w);
    }
    *(float4*)cp = v0;
    if constexpr (NH == 2) {
      float* cp1 = cp + 64;
      float4 v1 = make_float4(acc[i][4], acc[i][5], acc[i][6], acc[i][7]);
      if constexpr (EP == 1) {
        float4 o = *(const float4*)cp1;
        v1 = make_float4(o.x + v1.x, o.y + v1.y, o.z + v1.z, o.w + v1.w);
      }
      *(float4*)cp1 = v1;
    }
  }
}

// ---- fp32 GEMM 64x64x16, 4x4/thread — kept for N=48 (x_proj)
template<int EP>
__global__ __launch_bounds__(256) void gemm_nt(
    const float* __restrict__ A, const float* __restrict__ W, float* __restrict__ C,
    int M, int N, int K)
{
  __shared__ float As[16][68];
  __shared__ float Wsm[16][68];
  int tid = threadIdx.x;
  int bx = blockIdx.x, by = blockIdx.y;
  int tx = tid & 15, ty = tid >> 4;
  int lr = tid >> 2;
  int lk = (tid & 3) << 2;
  const float* Ap = A + (size_t)(bx * 64 + lr) * K + lk;
  int wrow = by * 64 + lr;
  bool wv = wrow < N;
  const float* Wp = W + (size_t)(wv ? wrow : 0) * K + lk;
  float acc[4][4];
#pragma unroll
  for (int i = 0; i < 4; ++i)
#pragma unroll
    for (int j = 0; j < 4; ++j) acc[i][j] = 0.0f;

#pragma unroll 1
  for (int k0 = 0; k0 < K; k0 += 16) {
    float4 av = *(const float4*)(Ap + k0);
    float4 wvv = wv ? *(const float4*)(Wp + k0) : make_float4(0.f, 0.f, 0.f, 0.f);
    __syncthreads();
    As[lk + 0][lr] = av.x; As[lk + 1][lr] = av.y; As[lk + 2][lr] = av.z; As[lk + 3][lr] = av.w;
    Wsm[lk + 0][lr] = wvv.x; Wsm[lk + 1][lr] = wvv.y; Wsm[lk + 2][lr] = wvv.z; Wsm[lk + 3][lr] = wvv.w;
    __syncthreads();
#pragma unroll
    for (int kk = 0; kk < 16; ++kk) {
      float4 a = *(const float4*)&As[kk][ty * 4];
      float4 b = *(const float4*)&Wsm[kk][tx * 4];
      acc[0][0] += a.x * b.x; acc[0][1] += a.x * b.y; acc[0][2] += a.x * b.z; acc[0][3] += a.x * b.w;
      acc[1][0] += a.y * b.x; acc[1][1] += a.y * b.y; acc[1][2] += a.y * b.z; acc[1][3] += a.y * b.w;
      acc[2][0] += a.z * b.x; acc[2][1] += a.z * b.y; acc[2][2] += a.z * b.z; acc[2][3] += a.z * b.w;
      acc[3][0] += a.w * b.x; acc[3][1] += a.w * b.y; acc[3][2] += a.w * b.z; acc[3][3] += a.w * b.w;
    }
  }
#pragma unroll
  for (int i = 0; i < 4; ++i) {
    int row = bx * 64 + ty * 4 + i;
    int col = by * 64 + tx * 4;
    float* cp = C + (size_t)row * N + col;
    if (col + 3 < N) {
      float4 o;
      if (EP == 1) {
        float4 old = *(const float4*)cp;
        o = make_float4(old.x + acc[i][0], old.y + acc[i][1], old.z + acc[i][2], old.w + acc[i][3]);
      } else {
        o = make_float4(acc[i][0], acc[i][1], acc[i][2], acc[i][3]);
      }
      *(float4*)cp = o;
    } else {
#pragma unroll
      for (int j = 0; j < 4; ++j) if (col + j < N) {
        float v = acc[i][j];
        if (EP == 1) v += cp[j];
        cp[j] = v;
      }
    }
  }
}

// ---- causal depthwise conv (K=4) + bias + SiLU, reading u-half of proj
__global__ __launch_bounds__(256) void conv_silu_kernel(
    const float* __restrict__ proj, const float* __restrict__ cw, const float* __restrict__ cb,
    float* __restrict__ u2)
{
  int idx = blockIdx.x * 256 + threadIdx.x;   // B*L*I = 4194304
  int i = idx & 511;
  int l = (idx >> 9) & 511;
  int bl = idx >> 9;
  const float* p = proj + (size_t)bl * 1024 + i;
  float4 w = *(const float4*)&cw[i * 4];
  float s = cb[i];
  s += (l >= 3) ? p[-3 * 1024] * w.x : 0.0f;
  s += (l >= 2) ? p[-2 * 1024] * w.y : 0.0f;
  s += (l >= 1) ? p[-1 * 1024] * w.z : 0.0f;
  s += p[0] * w.w;
  u2[idx] = siluf(s);
}

// ---- selective scan, dt-GEMM folded in. grid (I/64, B), 256 thr.
__global__ __launch_bounds__(256) void scan_kernel(
    const float* __restrict__ ssm, float* __restrict__ u2, const float* __restrict__ proj,
    const float* __restrict__ dtw, const float* __restrict__ dtb, const float* __restrict__ alog,
    const float* __restrict__ Dp)
{
  const int CL = 64;
  __shared__ float sbuf[CL * 48];
  __shared__ float ubuf[CL][64];
  __shared__ float gbuf[CL][64];
  int tid = threadIdx.x;
  int il = tid >> 2, ns = tid & 3;
  int i0 = blockIdx.x * 64;
  int i = i0 + il;
  int b = blockIdx.y;
  float A4[4], wr4[4];
#pragma unroll
  for (int nn = 0; nn < 4; ++nn) {
    A4[nn] = -__expf(alog[i * 16 + ns * 4 + nn]);
    wr4[nn] = dtw[i * 16 + ns * 4 + nn];
  }
  float dtbi = dtb[i], Di = Dp[i];
  float st0 = 0.f, st1 = 0.f, st2 = 0.f, st3 = 0.f;
  size_t rowL = (size_t)b * 512;

#pragma unroll 1
  for (int c = 0; c < 512; c += CL) {
    __syncthreads();
    {
      const float* src = ssm + (rowL + c) * 48;
      for (int t = tid; t < CL * 48; t += 256) sbuf[t] = src[t];
    }
    for (int t = tid; t < CL * 64; t += 256) {
      int lc = t >> 6, ci = t & 63;
      ubuf[lc][ci] = u2[(rowL + c + lc) * 512 + i0 + ci];
      gbuf[lc][ci] = proj[(rowL + c + lc) * 1024 + 512 + i0 + ci];
    }
    __syncthreads();
    for (int ll = 0; ll < CL; ++ll) {
      const float* row = &sbuf[ll * 48];
      float4 dtr = *(const float4*)(row + ns * 4);
      float pdt = dtr.x * wr4[0] + dtr.y * wr4[1] + dtr.z * wr4[2] + dtr.w * wr4[3];
      pdt += __shfl_xor(pdt, 1);
      pdt += __shfl_xor(pdt, 2);
      pdt += dtbi;
      float dtv = (pdt > 20.0f) ? pdt : __logf(1.0f + __expf(pdt));
      float u = ubuf[ll][il];
      float dtu = dtv * u;
      float4 Bv = *(const float4*)(row + 16 + ns * 4);
      float4 Cv = *(const float4*)(row + 32 + ns * 4);
      st0 = st0 * __expf(dtv * A4[0]) + dtu * Bv.x;
      st1 = st1 * __expf(dtv * A4[1]) + dtu * Bv.y;
      st2 = st2 * __expf(dtv * A4[2]) + dtu * Bv.z;
      st3 = st3 * __expf(dtv * A4[3]) + dtu * Bv.w;
      float yp = st0 * Cv.x + st1 * Cv.y + st2 * Cv.z + st3 * Cv.w;
      yp += __shfl_xor(yp, 1);
      yp += __shfl_xor(yp, 2);
      if (ns == 0) {
        float gt = gbuf[ll][il];
        ubuf[ll][il] = (yp + u * Di) * siluf(gt);
      }
    }
    __syncthreads();
    for (int t = tid; t < CL * 64; t += 256) {
      int lc = t >> 6, ci = t & 63;
      u2[(rowL + c + lc) * 512 + i0 + ci] = ubuf[lc][ci];
    }
  }
}

// ---- mean/max pool over L after final rmsnorm; writes emb into d_out+32
__global__ __launch_bounds__(64) void pool_kernel(const float* __restrict__ hn, float* __restrict__ outp)
{
  int c = blockIdx.x * 64 + threadIdx.x;
  int b = blockIdx.y;
  float s = 0.0f, mx = -3.4e38f;
  for (int l = 0; l < 512; ++l) {
    float v = hn[((size_t)b * 512 + l) * 256 + c];
    s += v;
    mx = fmaxf(mx, v);
  }
  outp[32 + b * 512 + c] = s * (1.0f / 512.0f);
  outp[32 + b * 512 + 256 + c] = mx;
}

// ---- KAN-2 head: (16, 512) -> (16, 2). One block per b.
__global__ __launch_bounds__(256) void kan2_kernel(
    const float* __restrict__ outp, const float* __restrict__ bw2, const float* __restrict__ sw2,
    const float* __restrict__ ss2, float* __restrict__ logits)
{
  __shared__ float r0[256], r1[256];
  int b = blockIdx.x, tid = threadIdx.x;
  float a0 = 0.0f, a1 = 0.0f;
#pragma unroll
  for (int dd = 0; dd < 2; ++dd) {
    int d = tid + dd * 256;
    float e = outp[32 + b * 512 + d];
    float bb[8];
    bspline8(e, bb);
    float sl = siluf(e);
    {
      float sc = ss2[d];
      const float* sp = &sw2[(size_t)d * 8];
      float t = sl * bw2[d];
      t += (bb[0] * sp[0] + bb[1] * sp[1] + bb[2] * sp[2] + bb[3] * sp[3]
          + bb[4] * sp[4] + bb[5] * sp[5] + bb[6] * sp[6] + bb[7] * sp[7]) * sc;
      a0 += t;
    }
    {
      float sc = ss2[512 + d];
      const float* sp = &sw2[(size_t)(512 + d) * 8];
      float t = sl * bw2[512 + d];
      t += (bb[0] * sp[0] + bb[1] * sp[1] + bb[2] * sp[2] + bb[3] * sp[3]
          + bb[4] * sp[4] + bb[5] * sp[5] + bb[6] * sp[6] + bb[7] * sp[7]) * sc;
      a1 += t;
    }
  }
  r0[tid] = a0; r1[tid] = a1;
  __syncthreads();
  for (int s = 128; s > 0; s >>= 1) {
    if (tid < s) { r0[tid] += r0[tid + s]; r1[tid] += r1[tid + s]; }
    __syncthreads();
  }
  if (tid == 0) { logits[b * 2 + 0] = r0[0]; logits[b * 2 + 1] = r1[0]; }
}

extern "C" void kernel_launch(void* const* d_in, const int* in_sizes, int n_in,
                              void* d_out, int out_size, void* d_ws, size_t ws_size,
                              hipStream_t stream)
{
  const float* x     = (const float*)d_in[0];
  const float* bw1   = (const float*)d_in[1];
  const float* sw1   = (const float*)d_in[2];
  const float* ss1   = (const float*)d_in[3];
  const float* lng   = (const float*)d_in[4];
  const float* lnb   = (const float*)d_in[5];
  const float* normw = (const float*)d_in[6];
  const float* ipw   = (const float*)d_in[7];
  const float* cw    = (const float*)d_in[8];
  const float* cb    = (const float*)d_in[9];
  const float* xpw   = (const float*)d_in[10];
  const float* dtw   = (const float*)d_in[11];
  const float* dtb   = (const float*)d_in[12];
  const float* alog  = (const float*)d_in[13];
  const float* Dp    = (const float*)d_in[14];
  const float* opw   = (const float*)d_in[15];
  const float* nfw   = (const float*)d_in[16];
  const float* bw2   = (const float*)d_in[17];
  const float* sw2   = (const float*)d_in[18];
  const float* ss2   = (const float*)d_in[19];
  float* out = (float*)d_out;

  float* ws   = (float*)d_ws;
  float* h    = ws;                       // 2097152 floats
  float* xn   = h + 2097152;              // 2097152
  float* proj = xn + 2097152;             // 8388608  (xT aliases this region pre-loop)
  float* u2   = proj + 8388608;           // 4194304
  float* ssmb = u2 + 4194304;             // 393216
  ushort* WTu = (ushort*)(ssmb + 393216); // 256*6912 u16 = 884736 floats
  float* xT   = proj;                     // 768*8192 = 6291456 floats <= 8388608 ✓
  // total: 18,055,168 floats ≈ 72.2 MB (≤ previously-proven 76 MB usage)

  prep_xT_kernel<<<dim3(128, 12), 256, 0, stream>>>(x, xT);
  prep_WT_kernel<<<dim3(27, 256), 256, 0, stream>>>(bw1, sw1, ss1, WTu);
  kan1_mfma_kernel<<<dim3(128, 2), 256, 0, stream>>>(xT, WTu, xn);   // raw kan1 -> xn
  layernorm_kernel<<<8192, 256, 0, stream>>>(xn, lng, lnb, h);       // h = LN(xn)

  for (int l = 0; l < 2; ++l) {
    rmsnorm_kernel<<<8192, 256, 0, stream>>>(h, normw + l * 256, xn);
    // in_proj: (8192,256)@(1024,256)^T -> (8192,1024)  [overwrites xT alias — xT is dead now]
    gemm128<2, 0><<<dim3(64, 8), 256, 0, stream>>>(xn, ipw + (size_t)l * 262144, proj, 1024, 256);
    conv_silu_kernel<<<16384, 256, 0, stream>>>(proj, cw + l * 2048, cb + l * 512, u2);
    // x_proj: (8192,512)@(48,512)^T -> (8192,48)
    gemm_nt<0><<<dim3(128, 1), 256, 0, stream>>>(u2, xpw + (size_t)l * 24576, ssmb, 8192, 48, 512);
    scan_kernel<<<dim3(8, 16), 256, 0, stream>>>(ssmb, u2, proj,
                                                 dtw + l * 8192, dtb + l * 512,
                                                 alog + l * 8192, Dp + l * 512);
    // out_proj (+residual): (8192,512)@(256,512)^T += h
    gemm128<1, 1><<<dim3(64, 4), 256, 0, stream>>>(u2, opw + (size_t)l * 131072, h, 256, 512);
  }

  rmsnorm_kernel<<<8192, 256, 0, stream>>>(h, nfw, xn);
  pool_kernel<<<dim3(4, 16), 64, 0, stream>>>(xn, out);
  kan2_kernel<<<16, 256, 0, stream>>>(out, bw2, sw2, ss2, out);
}

// Round 8
// 842.927 us; speedup vs baseline: 2.2240x; 1.3051x over previous
//
#include <hip/hip_runtime.h>
#include <cstdint>
#include <cstddef>

#define DIN 768
#define HD  256
#define LSEQ 512
#define IDIM 512

typedef __attribute__((ext_vector_type(8))) short bf16x8;
typedef __attribute__((ext_vector_type(4))) float f32x4;

__device__ __forceinline__ float siluf(float v) { return v / (1.0f + __expf(-v)); }

__device__ __forceinline__ ushort bf16rne(float v) {
  uint u = __float_as_uint(v);
  uint r = u + 0x7fffu + ((u >> 16) & 1u);
  return (ushort)(r >> 16);
}

// 8 cubic B-spline basis values (recursion form) — used by kan2 (tiny).
__device__ __forceinline__ void bspline8(float x, float* bb) {
  float b[11];
#pragma unroll
  for (int t = 0; t < 11; ++t) {
    float g0 = (float)(t - 3) * 0.4f - 1.0f;
    float g1 = (float)(t - 2) * 0.4f - 1.0f;
    b[t] = (x >= g0 && x < g1) ? 1.0f : 0.0f;
  }
#pragma unroll
  for (int kk = 1; kk <= 3; ++kk) {
#pragma unroll
    for (int t = 0; t + kk < 11; ++t) {
      float gt   = (float)(t - 3) * 0.4f - 1.0f;
      float gtk  = (float)(t + kk - 3) * 0.4f - 1.0f;
      float gtk1 = (float)(t + kk - 2) * 0.4f - 1.0f;
      float gt1  = (float)(t - 2) * 0.4f - 1.0f;
      float left  = (x - gt) * (1.0f / (gtk - gt));
      float right = (gtk1 - x) * (1.0f / (gtk1 - gt1));
      b[t] = left * b[t] + right * b[t + 1];
    }
  }
#pragma unroll
  for (int j = 0; j < 8; ++j) bb[j] = b[j];
}

// ---- transpose x (8192x768) -> xT (768x8192), LDS 64x64 tiles
__global__ __launch_bounds__(256) void prep_xT_kernel(
    const float* __restrict__ x, float* __restrict__ xT)
{
  __shared__ float tile[64][65];
  int t = threadIdx.x;
  int rb = t >> 6, c = t & 63;
  int n0 = blockIdx.x * 64, d0 = blockIdx.y * 64;
#pragma unroll
  for (int p = 0; p < 16; ++p) {
    int r = p * 4 + rb;
    tile[r][c] = x[(size_t)(n0 + r) * DIN + d0 + c];
  }
  __syncthreads();
#pragma unroll
  for (int p = 0; p < 16; ++p) {
    int r = p * 4 + rb;
    xT[(size_t)(d0 + r) * 8192 + n0 + c] = tile[c][r];
  }
}

// ---- pack kan1 weights bf16: WT[o][k], k<6144: spline(o,d=k/8,j=k%8)*ss; k>=6144: base
__global__ __launch_bounds__(256) void prep_WT_kernel(
    const float* __restrict__ bw, const float* __restrict__ sw, const float* __restrict__ ss,
    ushort* __restrict__ WT)
{
  int k = blockIdx.x * 256 + threadIdx.x;   // 0..6911 (27 blocks)
  int o = blockIdx.y;
  float v;
  if (k < 6144) {
    int d = k >> 3, j = k & 7;
    v = sw[((size_t)o * DIN + d) * 8 + j] * ss[(size_t)o * DIN + d];
  } else {
    v = bw[(size_t)o * DIN + (k - 6144)];
  }
  WT[(size_t)o * 6912 + k] = bf16rne(v);
}

// ---- KAN-1 as bf16 MFMA GEMM: C[8192,256] = A[8192,6912] @ WT^T.
__global__ __launch_bounds__(256) void kan1_mfma_kernel(
    const float* __restrict__ xT, const ushort* __restrict__ WT, float* __restrict__ xn)
{
  __shared__ __align__(16) ushort A_lds[64][40];
  __shared__ __align__(16) ushort B_lds[128][40];
  int tid = threadIdx.x;
  int l = tid & 63;
  int w = tid >> 6;
  int n0 = blockIdx.x * 64;
  int c0 = blockIdx.y * 128;

  f32x4 acc[4][2];
#pragma unroll
  for (int t = 0; t < 4; ++t)
#pragma unroll
    for (int ct = 0; ct < 2; ++ct)
#pragma unroll
      for (int i = 0; i < 4; ++i) acc[t][ct][i] = 0.0f;

  int ar = tid & 63;
  int aq = tid >> 6;
  int bc = tid & 127;
  int bh = tid >> 7;
  const ushort* wrow = &WT[(size_t)(c0 + bc) * 6912];

#pragma unroll 1
  for (int ks = 0; ks < 216; ++ks) {
    int k0 = ks * 32;
    __syncthreads();
    {
      const float4* src = (const float4*)(wrow + k0 + bh * 16);
      float4 v0 = src[0], v1 = src[1];
      float4* dst = (float4*)&B_lds[bc][bh * 16];
      dst[0] = v0; dst[1] = v1;
    }
    if (k0 < 6144) {
      int d = (k0 >> 3) + aq;
      float xv = xT[(size_t)d * 8192 + n0 + ar];
      float sxp = (xv + 2.2f) * 2.5f;
      float mf = floorf(sxp);
      int m = (int)mf;
      float u = sxp - mf;
      float uu = u * u, uuu = uu * u;
      float vmask = (m >= 0 && m <= 10) ? (1.0f / 6.0f) : 0.0f;
      float p0 = uuu * vmask;
      float p1 = (-3.f * uuu + 3.f * uu + 3.f * u + 1.f) * vmask;
      float p2 = (3.f * uuu - 6.f * uu + 4.f) * vmask;
      float om = 1.f - u;
      float p3 = om * om * om * vmask;
      ushort* arow = &A_lds[ar][aq * 8];
      *(float4*)arow = make_float4(0.f, 0.f, 0.f, 0.f);
      if (m >= 0 && m <= 7)  arow[m]     = bf16rne(p0);
      if (m >= 1 && m <= 8)  arow[m - 1] = bf16rne(p1);
      if (m >= 2 && m <= 9)  arow[m - 2] = bf16rne(p2);
      if (m >= 3 && m <= 10) arow[m - 3] = bf16rne(p3);
    } else {
      int db = (k0 - 6144) + aq * 8;
      uint pk[4];
#pragma unroll
      for (int i = 0; i < 4; ++i) {
        float x0 = xT[(size_t)(db + 2 * i) * 8192 + n0 + ar];
        float x1 = xT[(size_t)(db + 2 * i + 1) * 8192 + n0 + ar];
        pk[i] = (uint)bf16rne(siluf(x0)) | ((uint)bf16rne(siluf(x1)) << 16);
      }
      uint4* dst = (uint4*)&A_lds[ar][aq * 8];
      *dst = make_uint4(pk[0], pk[1], pk[2], pk[3]);
    }
    __syncthreads();
    bf16x8 bfr0 = *(bf16x8*)&B_lds[w * 32 + (l & 15)][(l >> 4) * 8];
    bf16x8 bfr1 = *(bf16x8*)&B_lds[w * 32 + 16 + (l & 15)][(l >> 4) * 8];
#pragma unroll
    for (int t = 0; t < 4; ++t) {
      bf16x8 afr = *(bf16x8*)&A_lds[t * 16 + (l & 15)][(l >> 4) * 8];
      acc[t][0] = __builtin_amdgcn_mfma_f32_16x16x32_bf16(afr, bfr0, acc[t][0], 0, 0, 0);
      acc[t][1] = __builtin_amdgcn_mfma_f32_16x16x32_bf16(afr, bfr1, acc[t][1], 0, 0, 0);
    }
  }
#pragma unroll
  for (int t = 0; t < 4; ++t)
#pragma unroll
    for (int ct = 0; ct < 2; ++ct)
#pragma unroll
      for (int i = 0; i < 4; ++i) {
        int row = n0 + t * 16 + (l >> 4) * 4 + i;
        int col = c0 + w * 32 + ct * 16 + (l & 15);
        xn[(size_t)row * HD + col] = acc[t][ct][i];
      }
}

// ---- LayerNorm: one block per row of 256 (full-H statistics)
__global__ __launch_bounds__(256) void layernorm_kernel(
    const float* __restrict__ in, const float* __restrict__ g, const float* __restrict__ b,
    float* __restrict__ out)
{
  __shared__ float pS[4], pQ[4];
  int row = blockIdx.x, tid = threadIdx.x;
  float v = in[(size_t)row * 256 + tid];
  float s = v, q = v * v;
#pragma unroll
  for (int off = 1; off < 64; off <<= 1) { s += __shfl_xor(s, off); q += __shfl_xor(q, off); }
  if ((tid & 63) == 0) { pS[tid >> 6] = s; pQ[tid >> 6] = q; }
  __syncthreads();
  float S = pS[0] + pS[1] + pS[2] + pS[3];
  float Q = pQ[0] + pQ[1] + pQ[2] + pQ[3];
  float m = S * (1.0f / 256.0f);
  float var = Q * (1.0f / 256.0f) - m * m;
  float rs = rsqrtf(var + 1e-5f);
  out[(size_t)row * 256 + tid] = (v - m) * rs * g[tid] + b[tid];
}

// ---- RMSNorm: one block per row of 256
__global__ __launch_bounds__(256) void rmsnorm_kernel(
    const float* __restrict__ in, const float* __restrict__ w, float* __restrict__ out)
{
  __shared__ float p[4];
  int row = blockIdx.x, tid = threadIdx.x;
  float v = in[(size_t)row * 256 + tid];
  float q = v * v;
#pragma unroll
  for (int off = 1; off < 64; off <<= 1) q += __shfl_xor(q, off);
  if ((tid & 63) == 0) p[tid >> 6] = q;
  __syncthreads();
  float s = p[0] + p[1] + p[2] + p[3];
  float rstd = rsqrtf(s * (1.0f / 256.0f) + 1e-5f);
  out[(size_t)row * 256 + tid] = w[tid] * v * rstd;
}

// ---- fp32 GEMM 128x(NH*64)x16, 256 threads, 8x(NH*4) per thread.
template<int NH, int EP>
__global__ __launch_bounds__(256) void gemm128(
    const float* __restrict__ A, const float* __restrict__ W, float* __restrict__ C,
    int N, int K)
{
  __shared__ float As[16][132];
  __shared__ float Wsm[16][NH * 64 + 4];
  int tid = threadIdx.x;
  int bx = blockIdx.x, by = blockIdx.y;
  int tx = tid & 15, ty = tid >> 4;
  int lr = tid >> 1;
  int lk = (tid & 1) << 3;
  int wr = (NH == 2) ? lr : (tid >> 2);
  int wk = (NH == 2) ? lk : ((tid & 3) << 2);
  const float* Ap = A + (size_t)(bx * 128 + lr) * K + lk;
  const float* Wp = W + (size_t)(by * (NH * 64) + wr) * K + wk;
  float acc[8][NH * 4];
#pragma unroll
  for (int i = 0; i < 8; ++i)
#pragma unroll
    for (int j = 0; j < NH * 4; ++j) acc[i][j] = 0.0f;

#pragma unroll 1
  for (int k0 = 0; k0 < K; k0 += 16) {
    float4 av0 = *(const float4*)(Ap + k0);
    float4 av1 = *(const float4*)(Ap + k0 + 4);
    float4 wv0 = *(const float4*)(Wp + k0);
    float4 wv1;
    if constexpr (NH == 2) wv1 = *(const float4*)(Wp + k0 + 4);
    __syncthreads();
    As[lk + 0][lr] = av0.x; As[lk + 1][lr] = av0.y; As[lk + 2][lr] = av0.z; As[lk + 3][lr] = av0.w;
    As[lk + 4][lr] = av1.x; As[lk + 5][lr] = av1.y; As[lk + 6][lr] = av1.z; As[lk + 7][lr] = av1.w;
    Wsm[wk + 0][wr] = wv0.x; Wsm[wk + 1][wr] = wv0.y; Wsm[wk + 2][wr] = wv0.z; Wsm[wk + 3][wr] = wv0.w;
    if constexpr (NH == 2) {
      Wsm[wk + 4][wr] = wv1.x; Wsm[wk + 5][wr] = wv1.y; Wsm[wk + 6][wr] = wv1.z; Wsm[wk + 7][wr] = wv1.w;
    }
    __syncthreads();
#pragma unroll
    for (int kk = 0; kk < 16; ++kk) {
      float4 a0 = *(const float4*)&As[kk][ty * 4];
      float4 a1 = *(const float4*)&As[kk][64 + ty * 4];
      float af[8] = {a0.x, a0.y, a0.z, a0.w, a1.x, a1.y, a1.z, a1.w};
      float wf[8];
      float4 b0 = *(const float4*)&Wsm[kk][tx * 4];
      wf[0] = b0.x; wf[1] = b0.y; wf[2] = b0.z; wf[3] = b0.w;
      if constexpr (NH == 2) {
        float4 b1 = *(const float4*)&Wsm[kk][64 + tx * 4];
        wf[4] = b1.x; wf[5] = b1.y; wf[6] = b1.z; wf[7] = b1.w;
      }
#pragma unroll
      for (int i = 0; i < 8; ++i)
#pragma unroll
        for (int j = 0; j < NH * 4; ++j)
          acc[i][j] += af[i] * wf[j];
    }
  }
#pragma unroll
  for (int i = 0; i < 8; ++i) {
    int rloc = (i < 4) ? (ty * 4 + i) : (60 + ty * 4 + i);
    float* cp = C + (size_t)(bx * 128 + rloc) * N + by * (NH * 64) + tx * 4;
    float4 v0 = make_float4(acc[i][0], acc[i][1], acc[i][2], acc[i][3]);
    if constexpr (EP == 1) {
      float4 o = *(const float4*)cp;
      v0 = make_float4(o.x + v0.x, o.y + v0.y, o.z + v0.z, o.w + v0.w);
    }
    *(float4*)cp = v0;
    if constexpr (NH == 2) {
      float* cp1 = cp + 64;
      float4 v1 = make_float4(acc[i][4], acc[i][5], acc[i][6], acc[i][7]);
      if constexpr (EP == 1) {
        float4 o = *(const float4*)cp1;
        v1 = make_float4(o.x + v1.x, o.y + v1.y, o.z + v1.z, o.w + v1.w);
      }
      *(float4*)cp1 = v1;
    }
  }
}

// ---- fp32 GEMM 64x64x16, 4x4/thread — kept for N=48 (x_proj)
template<int EP>
__global__ __launch_bounds__(256) void gemm_nt(
    const float* __restrict__ A, const float* __restrict__ W, float* __restrict__ C,
    int M, int N, int K)
{
  __shared__ float As[16][68];
  __shared__ float Wsm[16][68];
  int tid = threadIdx.x;
  int bx = blockIdx.x, by = blockIdx.y;
  int tx = tid & 15, ty = tid >> 4;
  int lr = tid >> 2;
  int lk = (tid & 3) << 2;
  const float* Ap = A + (size_t)(bx * 64 + lr) * K + lk;
  int wrow = by * 64 + lr;
  bool wv = wrow < N;
  const float* Wp = W + (size_t)(wv ? wrow : 0) * K + lk;
  float acc[4][4];
#pragma unroll
  for (int i = 0; i < 4; ++i)
#pragma unroll
    for (int j = 0; j < 4; ++j) acc[i][j] = 0.0f;

#pragma unroll 1
  for (int k0 = 0; k0 < K; k0 += 16) {
    float4 av = *(const float4*)(Ap + k0);
    float4 wvv = wv ? *(const float4*)(Wp + k0) : make_float4(0.f, 0.f, 0.f, 0.f);
    __syncthreads();
    As[lk + 0][lr] = av.x; As[lk + 1][lr] = av.y; As[lk + 2][lr] = av.z; As[lk + 3][lr] = av.w;
    Wsm[lk + 0][lr] = wvv.x; Wsm[lk + 1][lr] = wvv.y; Wsm[lk + 2][lr] = wvv.z; Wsm[lk + 3][lr] = wvv.w;
    __syncthreads();
#pragma unroll
    for (int kk = 0; kk < 16; ++kk) {
      float4 a = *(const float4*)&As[kk][ty * 4];
      float4 b = *(const float4*)&Wsm[kk][tx * 4];
      acc[0][0] += a.x * b.x; acc[0][1] += a.x * b.y; acc[0][2] += a.x * b.z; acc[0][3] += a.x * b.w;
      acc[1][0] += a.y * b.x; acc[1][1] += a.y * b.y; acc[1][2] += a.y * b.z; acc[1][3] += a.y * b.w;
      acc[2][0] += a.z * b.x; acc[2][1] += a.z * b.y; acc[2][2] += a.z * b.z; acc[2][3] += a.z * b.w;
      acc[3][0] += a.w * b.x; acc[3][1] += a.w * b.y; acc[3][2] += a.w * b.z; acc[3][3] += a.w * b.w;
    }
  }
#pragma unroll
  for (int i = 0; i < 4; ++i) {
    int row = bx * 64 + ty * 4 + i;
    int col = by * 64 + tx * 4;
    float* cp = C + (size_t)row * N + col;
    if (col + 3 < N) {
      float4 o;
      if (EP == 1) {
        float4 old = *(const float4*)cp;
        o = make_float4(old.x + acc[i][0], old.y + acc[i][1], old.z + acc[i][2], old.w + acc[i][3]);
      } else {
        o = make_float4(acc[i][0], acc[i][1], acc[i][2], acc[i][3]);
      }
      *(float4*)cp = o;
    } else {
#pragma unroll
      for (int j = 0; j < 4; ++j) if (col + j < N) {
        float v = acc[i][j];
        if (EP == 1) v += cp[j];
        cp[j] = v;
      }
    }
  }
}

// ---- causal depthwise conv (K=4) + bias + SiLU, reading u-half of proj
__global__ __launch_bounds__(256) void conv_silu_kernel(
    const float* __restrict__ proj, const float* __restrict__ cw, const float* __restrict__ cb,
    float* __restrict__ u2)
{
  int idx = blockIdx.x * 256 + threadIdx.x;   // B*L*I = 4194304
  int i = idx & 511;
  int l = (idx >> 9) & 511;
  int bl = idx >> 9;
  const float* p = proj + (size_t)bl * 1024 + i;
  float4 w = *(const float4*)&cw[i * 4];
  float s = cb[i];
  s += (l >= 3) ? p[-3 * 1024] * w.x : 0.0f;
  s += (l >= 2) ? p[-2 * 1024] * w.y : 0.0f;
  s += (l >= 1) ? p[-1 * 1024] * w.z : 0.0f;
  s += p[0] * w.w;
  u2[idx] = siluf(s);
}

// ---- scan pass 1: per-chunk local scan (from 0) + dA product.
// grid (8 iblk, 16 b, 8 lc), 256 thr: il=tid>>2 (i in block), ns=tid&3 (4 states).
__global__ __launch_bounds__(256) void scan_part1_kernel(
    const float* __restrict__ ssm, const float* __restrict__ u2,
    const float* __restrict__ dtw, const float* __restrict__ dtb, const float* __restrict__ alog,
    float* __restrict__ Sg, float* __restrict__ Pg)
{
  const int CL = 64;
  __shared__ float sbuf[CL * 32];      // dt(16) + B(16) per row
  __shared__ float ubuf[CL][64];
  int tid = threadIdx.x;
  int il = tid >> 2, ns = tid & 3;
  int i0 = blockIdx.x * 64;
  int b = blockIdx.y;
  int lc = blockIdx.z;
  int i = i0 + il;
  float A4[4], wr4[4];
#pragma unroll
  for (int nn = 0; nn < 4; ++nn) {
    A4[nn] = -__expf(alog[i * 16 + ns * 4 + nn]);
    wr4[nn] = dtw[i * 16 + ns * 4 + nn];
  }
  float dtbi = dtb[i];
  size_t rowL = (size_t)b * 512 + lc * CL;

  for (int t = tid; t < CL * 32; t += 256) {
    int r = t >> 5, c = t & 31;
    sbuf[t] = ssm[(rowL + r) * 48 + c];
  }
  for (int t = tid; t < CL * 64; t += 256) {
    int lr = t >> 6, ci = t & 63;
    ubuf[lr][ci] = u2[(rowL + lr) * 512 + i0 + ci];
  }
  __syncthreads();

  float s0 = 0.f, s1 = 0.f, s2 = 0.f, s3 = 0.f;
  float p0 = 1.f, p1 = 1.f, p2 = 1.f, p3 = 1.f;
  for (int ll = 0; ll < CL; ++ll) {
    const float* row = &sbuf[ll * 32];
    float4 dtr = *(const float4*)(row + ns * 4);
    float pdt = dtr.x * wr4[0] + dtr.y * wr4[1] + dtr.z * wr4[2] + dtr.w * wr4[3];
    pdt += __shfl_xor(pdt, 1);
    pdt += __shfl_xor(pdt, 2);
    pdt += dtbi;
    float dtv = (pdt > 20.0f) ? pdt : __logf(1.0f + __expf(pdt));
    float u = ubuf[ll][il];
    float dtu = dtv * u;
    float4 Bv = *(const float4*)(row + 16 + ns * 4);
    float e0 = __expf(dtv * A4[0]);
    float e1 = __expf(dtv * A4[1]);
    float e2 = __expf(dtv * A4[2]);
    float e3 = __expf(dtv * A4[3]);
    s0 = s0 * e0 + dtu * Bv.x;  p0 *= e0;
    s1 = s1 * e1 + dtu * Bv.y;  p1 *= e1;
    s2 = s2 * e2 + dtu * Bv.z;  p2 *= e2;
    s3 = s3 * e3 + dtu * Bv.w;  p3 *= e3;
  }
  size_t off = ((size_t)(b * 8 + lc) * 512 + i) * 16 + ns * 4;
  Sg[off + 0] = s0; Sg[off + 1] = s1; Sg[off + 2] = s2; Sg[off + 3] = s3;
  Pg[off + 0] = p0; Pg[off + 1] = p1; Pg[off + 2] = p2; Pg[off + 3] = p3;
}

// ---- scan pass 2 (combine): s_in across chunks; overwrites Sg with incoming state.
__global__ __launch_bounds__(256) void scan_combine_kernel(
    float* __restrict__ Sg, const float* __restrict__ Pg)
{
  int gid = blockIdx.x * 256 + threadIdx.x;   // B*I*N = 131072
  int b = gid >> 13;
  int rest = gid & 8191;                      // i*16+n
  float sin = 0.f;
#pragma unroll
  for (int lc = 0; lc < 8; ++lc) {
    size_t off = (size_t)(b * 8 + lc) * 8192 + rest;
    float S = Sg[off], P = Pg[off];
    Sg[off] = sin;
    sin = sin * P + S;
  }
}

// ---- scan pass 3: recompute chunk scan from incoming state, fuse y/D/gate.
__global__ __launch_bounds__(256) void scan_part2_kernel(
    const float* __restrict__ ssm, float* __restrict__ u2, const float* __restrict__ proj,
    const float* __restrict__ dtw, const float* __restrict__ dtb, const float* __restrict__ alog,
    const float* __restrict__ Dp, const float* __restrict__ Sg)
{
  const int CL = 64;
  __shared__ float sbuf[CL * 48];
  __shared__ float ubuf[CL][64];
  __shared__ float gbuf[CL][64];
  int tid = threadIdx.x;
  int il = tid >> 2, ns = tid & 3;
  int i0 = blockIdx.x * 64;
  int b = blockIdx.y;
  int lc = blockIdx.z;
  int i = i0 + il;
  float A4[4], wr4[4];
#pragma unroll
  for (int nn = 0; nn < 4; ++nn) {
    A4[nn] = -__expf(alog[i * 16 + ns * 4 + nn]);
    wr4[nn] = dtw[i * 16 + ns * 4 + nn];
  }
  float dtbi = dtb[i], Di = Dp[i];
  size_t rowL = (size_t)b * 512 + lc * CL;
  size_t soff = ((size_t)(b * 8 + lc) * 512 + i) * 16 + ns * 4;
  float st0 = Sg[soff + 0], st1 = Sg[soff + 1], st2 = Sg[soff + 2], st3 = Sg[soff + 3];

  for (int t = tid; t < CL * 48; t += 256) {
    sbuf[t] = ssm[rowL * 48 + t];
  }
  for (int t = tid; t < CL * 64; t += 256) {
    int lr = t >> 6, ci = t & 63;
    ubuf[lr][ci] = u2[(rowL + lr) * 512 + i0 + ci];
    gbuf[lr][ci] = proj[(rowL + lr) * 1024 + 512 + i0 + ci];
  }
  __syncthreads();

  for (int ll = 0; ll < CL; ++ll) {
    const float* row = &sbuf[ll * 48];
    float4 dtr = *(const float4*)(row + ns * 4);
    float pdt = dtr.x * wr4[0] + dtr.y * wr4[1] + dtr.z * wr4[2] + dtr.w * wr4[3];
    pdt += __shfl_xor(pdt, 1);
    pdt += __shfl_xor(pdt, 2);
    pdt += dtbi;
    float dtv = (pdt > 20.0f) ? pdt : __logf(1.0f + __expf(pdt));
    float u = ubuf[ll][il];
    float dtu = dtv * u;
    float4 Bv = *(const float4*)(row + 16 + ns * 4);
    float4 Cv = *(const float4*)(row + 32 + ns * 4);
    st0 = st0 * __expf(dtv * A4[0]) + dtu * Bv.x;
    st1 = st1 * __expf(dtv * A4[1]) + dtu * Bv.y;
    st2 = st2 * __expf(dtv * A4[2]) + dtu * Bv.z;
    st3 = st3 * __expf(dtv * A4[3]) + dtu * Bv.w;
    float yp = st0 * Cv.x + st1 * Cv.y + st2 * Cv.z + st3 * Cv.w;
    yp += __shfl_xor(yp, 1);
    yp += __shfl_xor(yp, 2);
    if (ns == 0) {
      float gt = gbuf[ll][il];
      ubuf[ll][il] = (yp + u * Di) * siluf(gt);
    }
  }
  __syncthreads();
  for (int t = tid; t < CL * 64; t += 256) {
    int lr = t >> 6, ci = t & 63;
    u2[(rowL + lr) * 512 + i0 + ci] = ubuf[lr][ci];
  }
}

// ---- mean/max pool over L after final rmsnorm; writes emb into d_out+32
__global__ __launch_bounds__(64) void pool_kernel(const float* __restrict__ hn, float* __restrict__ outp)
{
  int c = blockIdx.x * 64 + threadIdx.x;
  int b = blockIdx.y;
  float s = 0.0f, mx = -3.4e38f;
  for (int l = 0; l < 512; ++l) {
    float v = hn[((size_t)b * 512 + l) * 256 + c];
    s += v;
    mx = fmaxf(mx, v);
  }
  outp[32 + b * 512 + c] = s * (1.0f / 512.0f);
  outp[32 + b * 512 + 256 + c] = mx;
}

// ---- KAN-2 head: (16, 512) -> (16, 2). One block per b.
__global__ __launch_bounds__(256) void kan2_kernel(
    const float* __restrict__ outp, const float* __restrict__ bw2, const float* __restrict__ sw2,
    const float* __restrict__ ss2, float* __restrict__ logits)
{
  __shared__ float r0[256], r1[256];
  int b = blockIdx.x, tid = threadIdx.x;
  float a0 = 0.0f, a1 = 0.0f;
#pragma unroll
  for (int dd = 0; dd < 2; ++dd) {
    int d = tid + dd * 256;
    float e = outp[32 + b * 512 + d];
    float bb[8];
    bspline8(e, bb);
    float sl = siluf(e);
    {
      float sc = ss2[d];
      const float* sp = &sw2[(size_t)d * 8];
      float t = sl * bw2[d];
      t += (bb[0] * sp[0] + bb[1] * sp[1] + bb[2] * sp[2] + bb[3] * sp[3]
          + bb[4] * sp[4] + bb[5] * sp[5] + bb[6] * sp[6] + bb[7] * sp[7]) * sc;
      a0 += t;
    }
    {
      float sc = ss2[512 + d];
      const float* sp = &sw2[(size_t)(512 + d) * 8];
      float t = sl * bw2[512 + d];
      t += (bb[0] * sp[0] + bb[1] * sp[1] + bb[2] * sp[2] + bb[3] * sp[3]
          + bb[4] * sp[4] + bb[5] * sp[5] + bb[6] * sp[6] + bb[7] * sp[7]) * sc;
      a1 += t;
    }
  }
  r0[tid] = a0; r1[tid] = a1;
  __syncthreads();
  for (int s = 128; s > 0; s >>= 1) {
    if (tid < s) { r0[tid] += r0[tid + s]; r1[tid] += r1[tid + s]; }
    __syncthreads();
  }
  if (tid == 0) { logits[b * 2 + 0] = r0[0]; logits[b * 2 + 1] = r1[0]; }
}

extern "C" void kernel_launch(void* const* d_in, const int* in_sizes, int n_in,
                              void* d_out, int out_size, void* d_ws, size_t ws_size,
                              hipStream_t stream)
{
  const float* x     = (const float*)d_in[0];
  const float* bw1   = (const float*)d_in[1];
  const float* sw1   = (const float*)d_in[2];
  const float* ss1   = (const float*)d_in[3];
  const float* lng   = (const float*)d_in[4];
  const float* lnb   = (const float*)d_in[5];
  const float* normw = (const float*)d_in[6];
  const float* ipw   = (const float*)d_in[7];
  const float* cw    = (const float*)d_in[8];
  const float* cb    = (const float*)d_in[9];
  const float* xpw   = (const float*)d_in[10];
  const float* dtw   = (const float*)d_in[11];
  const float* dtb   = (const float*)d_in[12];
  const float* alog  = (const float*)d_in[13];
  const float* Dp    = (const float*)d_in[14];
  const float* opw   = (const float*)d_in[15];
  const float* nfw   = (const float*)d_in[16];
  const float* bw2   = (const float*)d_in[17];
  const float* sw2   = (const float*)d_in[18];
  const float* ss2   = (const float*)d_in[19];
  float* out = (float*)d_out;

  float* ws   = (float*)d_ws;
  float* h    = ws;                       // 2097152 floats
  float* xn   = h + 2097152;              // 2097152
  float* proj = xn + 2097152;             // 8388608  (xT aliases pre-loop)
  float* u2   = proj + 8388608;           // 4194304
  float* ssmb = u2 + 4194304;             // 393216
  ushort* WTu = (ushort*)(ssmb + 393216); // 884736 floats worth
  float* xT   = proj;                     // 6291456 <= 8388608 ✓
  float* Sg   = xn;                       // 1048576 (xn dead during scan)
  float* Pg   = xn + 1048576;             // 1048576 — exactly fills xn ✓
  // total unchanged ≈ 72.2 MB

  prep_xT_kernel<<<dim3(128, 12), 256, 0, stream>>>(x, xT);
  prep_WT_kernel<<<dim3(27, 256), 256, 0, stream>>>(bw1, sw1, ss1, WTu);
  kan1_mfma_kernel<<<dim3(128, 2), 256, 0, stream>>>(xT, WTu, xn);
  layernorm_kernel<<<8192, 256, 0, stream>>>(xn, lng, lnb, h);

  for (int l = 0; l < 2; ++l) {
    rmsnorm_kernel<<<8192, 256, 0, stream>>>(h, normw + l * 256, xn);
    gemm128<2, 0><<<dim3(64, 8), 256, 0, stream>>>(xn, ipw + (size_t)l * 262144, proj, 1024, 256);
    conv_silu_kernel<<<16384, 256, 0, stream>>>(proj, cw + l * 2048, cb + l * 512, u2);
    gemm_nt<0><<<dim3(128, 1), 256, 0, stream>>>(u2, xpw + (size_t)l * 24576, ssmb, 8192, 48, 512);
    // chunked selective scan (xn is dead here; Sg/Pg alias it)
    scan_part1_kernel<<<dim3(8, 16, 8), 256, 0, stream>>>(ssmb, u2,
        dtw + l * 8192, dtb + l * 512, alog + l * 8192, Sg, Pg);
    scan_combine_kernel<<<512, 256, 0, stream>>>(Sg, Pg);
    scan_part2_kernel<<<dim3(8, 16, 8), 256, 0, stream>>>(ssmb, u2, proj,
        dtw + l * 8192, dtb + l * 512, alog + l * 8192, Dp + l * 512, Sg);
    gemm128<1, 1><<<dim3(64, 4), 256, 0, stream>>>(u2, opw + (size_t)l * 131072, h, 256, 512);
  }

  rmsnorm_kernel<<<8192, 256, 0, stream>>>(h, nfw, xn);
  pool_kernel<<<dim3(4, 16), 64, 0, stream>>>(xn, out);
  kan2_kernel<<<16, 256, 0, stream>>>(out, bw2, sw2, ss2, out);
}

// Round 9
// 640.178 us; speedup vs baseline: 2.9283x; 1.3167x over previous
//
#include <hip/hip_runtime.h>
#include <cstdint>
#include <cstddef>

#define DIN 768
#define HD  256
#define LSEQ 512
#define IDIM 512

typedef __attribute__((ext_vector_type(8))) short bf16x8;
typedef __attribute__((ext_vector_type(4))) float f32x4;

__device__ __forceinline__ float siluf(float v) { return v / (1.0f + __expf(-v)); }

__device__ __forceinline__ ushort bf16rne(float v) {
  uint u = __float_as_uint(v);
  uint r = u + 0x7fffu + ((u >> 16) & 1u);
  return (ushort)(r >> 16);
}
__device__ __forceinline__ uint pack2bf(float a, float b) {
  return (uint)bf16rne(a) | ((uint)bf16rne(b) << 16);
}

// 8 cubic B-spline basis values (recursion form) — used by kan2 (tiny).
__device__ __forceinline__ void bspline8(float x, float* bb) {
  float b[11];
#pragma unroll
  for (int t = 0; t < 11; ++t) {
    float g0 = (float)(t - 3) * 0.4f - 1.0f;
    float g1 = (float)(t - 2) * 0.4f - 1.0f;
    b[t] = (x >= g0 && x < g1) ? 1.0f : 0.0f;
  }
#pragma unroll
  for (int kk = 1; kk <= 3; ++kk) {
#pragma unroll
    for (int t = 0; t + kk < 11; ++t) {
      float gt   = (float)(t - 3) * 0.4f - 1.0f;
      float gtk  = (float)(t + kk - 3) * 0.4f - 1.0f;
      float gtk1 = (float)(t + kk - 2) * 0.4f - 1.0f;
      float gt1  = (float)(t - 2) * 0.4f - 1.0f;
      float left  = (x - gt) * (1.0f / (gtk - gt));
      float right = (gtk1 - x) * (1.0f / (gtk1 - gt1));
      b[t] = left * b[t] + right * b[t + 1];
    }
  }
#pragma unroll
  for (int j = 0; j < 8; ++j) bb[j] = b[j];
}

// ---- transpose x (8192x768) -> xT (768x8192)
__global__ __launch_bounds__(256) void prep_xT_kernel(
    const float* __restrict__ x, float* __restrict__ xT)
{
  __shared__ float tile[64][65];
  int t = threadIdx.x;
  int rb = t >> 6, c = t & 63;
  int n0 = blockIdx.x * 64, d0 = blockIdx.y * 64;
#pragma unroll
  for (int p = 0; p < 16; ++p) {
    int r = p * 4 + rb;
    tile[r][c] = x[(size_t)(n0 + r) * DIN + d0 + c];
  }
  __syncthreads();
#pragma unroll
  for (int p = 0; p < 16; ++p) {
    int r = p * 4 + rb;
    xT[(size_t)(d0 + r) * 8192 + n0 + c] = tile[c][r];
  }
}

// ---- pack kan1 weights bf16: WT[o][k]
__global__ __launch_bounds__(256) void prep_WT_kernel(
    const float* __restrict__ bw, const float* __restrict__ sw, const float* __restrict__ ss,
    ushort* __restrict__ WT)
{
  int k = blockIdx.x * 256 + threadIdx.x;   // 0..6911
  int o = blockIdx.y;
  float v;
  if (k < 6144) {
    int d = k >> 3, j = k & 7;
    v = sw[((size_t)o * DIN + d) * 8 + j] * ss[(size_t)o * DIN + d];
  } else {
    v = bw[(size_t)o * DIN + (k - 6144)];
  }
  WT[(size_t)o * 6912 + k] = bf16rne(v);
}

// ---- generic fp32 -> bf16 pack
__global__ __launch_bounds__(256) void pack_bf16_kernel(
    const float* __restrict__ src, ushort* __restrict__ dst)
{
  int i = blockIdx.x * 256 + threadIdx.x;
  dst[i] = bf16rne(src[i]);
}

// ---- KAN-1 bf16 MFMA GEMM, split-K (z=0: ks 0..107, z=1: ks 108..215).
// Branchless A staging (cndmask select, single uint4 LDS write) + T14 prefetch.
__global__ __launch_bounds__(256) void kan1_mfma_kernel(
    const float* __restrict__ xT, const ushort* __restrict__ WT,
    float* __restrict__ outA, float* __restrict__ outB)
{
  __shared__ __align__(16) ushort A_lds[64][40];
  __shared__ __align__(16) ushort B_lds[128][40];
  int tid = threadIdx.x;
  int l = tid & 63;
  int w = tid >> 6;
  int n0 = blockIdx.x * 64;
  int c0 = blockIdx.y * 128;
  int z = blockIdx.z;
  int ksb = z * 108, kse = ksb + 108;
  float* xn = z ? outB : outA;

  f32x4 acc[4][2];
#pragma unroll
  for (int t = 0; t < 4; ++t)
#pragma unroll
    for (int ct = 0; ct < 2; ++ct)
#pragma unroll
      for (int i = 0; i < 4; ++i) acc[t][ct][i] = 0.0f;

  int ar = tid & 63;
  int aq = tid >> 6;
  int bc = tid & 127;
  int bh = tid >> 7;
  const ushort* wrow = &WT[(size_t)(c0 + bc) * 6912];

  float pa[8];
  float4 pb0, pb1;

  auto prefetch = [&](int ks) {
    int k0 = ks * 32;
    const float4* src = (const float4*)(wrow + k0 + bh * 16);
    pb0 = src[0]; pb1 = src[1];
    if (k0 < 6144) {
      int d = (k0 >> 3) + aq;
      pa[0] = xT[(size_t)d * 8192 + n0 + ar];
    } else {
      int db = (k0 - 6144) + aq * 8;
#pragma unroll
      for (int i = 0; i < 8; ++i)
        pa[i] = xT[(size_t)(db + i) * 8192 + n0 + ar];
    }
  };

  prefetch(ksb);

#pragma unroll 1
  for (int ks = ksb; ks < kse; ++ks) {
    int k0 = ks * 32;
    uint4 aval;
    if (k0 < 6144) {
      float xv = pa[0];
      float sxp = (xv + 2.2f) * 2.5f;
      float mf = floorf(sxp);
      int m = (int)mf;
      float u = sxp - mf;
      float uu = u * u, uuu = uu * u;
      float vmask = (m >= 0 && m <= 10) ? (1.0f / 6.0f) : 0.0f;
      float p0 = uuu * vmask;
      float p1 = (-3.f * uuu + 3.f * uu + 3.f * u + 1.f) * vmask;
      float p2 = (3.f * uuu - 6.f * uu + 4.f) * vmask;
      float om = 1.f - u;
      float p3 = om * om * om * vmask;
      float vj[8];
#pragma unroll
      for (int j = 0; j < 8; ++j) {
        float v = 0.f;
        v = (m == j)     ? p0 : v;
        v = (m == j + 1) ? p1 : v;
        v = (m == j + 2) ? p2 : v;
        v = (m == j + 3) ? p3 : v;
        vj[j] = v;
      }
      aval = make_uint4(pack2bf(vj[0], vj[1]), pack2bf(vj[2], vj[3]),
                        pack2bf(vj[4], vj[5]), pack2bf(vj[6], vj[7]));
    } else {
      aval = make_uint4(pack2bf(siluf(pa[0]), siluf(pa[1])),
                        pack2bf(siluf(pa[2]), siluf(pa[3])),
                        pack2bf(siluf(pa[4]), siluf(pa[5])),
                        pack2bf(siluf(pa[6]), siluf(pa[7])));
    }
    float4 wb0 = pb0, wb1 = pb1;
    __syncthreads();               // previous LDS fully consumed
    {
      float4* dst = (float4*)&B_lds[bc][bh * 16];
      dst[0] = wb0; dst[1] = wb1;
      *(uint4*)&A_lds[ar][aq * 8] = aval;
    }
    __syncthreads();
    if (ks + 1 < kse) prefetch(ks + 1);   // loads fly during MFMA below
    bf16x8 bfr0 = *(bf16x8*)&B_lds[w * 32 + (l & 15)][(l >> 4) * 8];
    bf16x8 bfr1 = *(bf16x8*)&B_lds[w * 32 + 16 + (l & 15)][(l >> 4) * 8];
#pragma unroll
    for (int t = 0; t < 4; ++t) {
      bf16x8 afr = *(bf16x8*)&A_lds[t * 16 + (l & 15)][(l >> 4) * 8];
      acc[t][0] = __builtin_amdgcn_mfma_f32_16x16x32_bf16(afr, bfr0, acc[t][0], 0, 0, 0);
      acc[t][1] = __builtin_amdgcn_mfma_f32_16x16x32_bf16(afr, bfr1, acc[t][1], 0, 0, 0);
    }
  }
#pragma unroll
  for (int t = 0; t < 4; ++t)
#pragma unroll
    for (int ct = 0; ct < 2; ++ct)
#pragma unroll
      for (int i = 0; i < 4; ++i) {
        int row = n0 + t * 16 + (l >> 4) * 4 + i;
        int col = c0 + w * 32 + ct * 16 + (l & 15);
        xn[(size_t)row * HD + col] = acc[t][ct][i];
      }
}

// ---- generic bf16 MFMA GEMM: C[M][N] = A_fp32[M][K] @ WB_bf16[N][K]^T (+C if EP)
// CT = 16-col tiles per wave (2 -> BN=128, 1 -> BN=64). K%32==0.
template<int CT, int EP>
__global__ __launch_bounds__(256) void mfma_gemm(
    const float* __restrict__ A, const ushort* __restrict__ WB, float* __restrict__ C,
    int N, int K)
{
  constexpr int BN = CT * 64;
  __shared__ __align__(16) ushort A_lds[64][40];
  __shared__ __align__(16) ushort B_lds[BN][40];
  int tid = threadIdx.x;
  int l = tid & 63;
  int w = tid >> 6;
  int n0 = blockIdx.x * 64;
  int c0 = blockIdx.y * BN;

  f32x4 acc[4][CT];
#pragma unroll
  for (int t = 0; t < 4; ++t)
#pragma unroll
    for (int ct = 0; ct < CT; ++ct)
#pragma unroll
      for (int i = 0; i < 4; ++i) acc[t][ct][i] = 0.0f;

  int ar = tid & 63;
  int aq = tid >> 6;
  int bc, bh;
  if constexpr (CT == 2) { bc = tid & 127; bh = tid >> 7; }
  else                   { bc = tid & 63;  bh = tid >> 6; }
  const ushort* wrow = &WB[(size_t)(c0 + bc) * K];
  const float* arow = &A[(size_t)(n0 + ar) * K];
  int nk = K >> 5;

#pragma unroll 1
  for (int ks = 0; ks < nk; ++ks) {
    int k0 = ks * 32;
    // issue global reads before the barrier (latency overlaps barrier wait)
    float4 a0 = *(const float4*)(arow + k0 + aq * 8);
    float4 a1 = *(const float4*)(arow + k0 + aq * 8 + 4);
    float4 bv0, bv1;
    if constexpr (CT == 2) {
      const float4* src = (const float4*)(wrow + k0 + bh * 16);
      bv0 = src[0]; bv1 = src[1];
    } else {
      bv0 = *(const float4*)(wrow + k0 + bh * 8);
    }
    uint4 aval = make_uint4(pack2bf(a0.x, a0.y), pack2bf(a0.z, a0.w),
                            pack2bf(a1.x, a1.y), pack2bf(a1.z, a1.w));
    __syncthreads();
    if constexpr (CT == 2) {
      float4* dst = (float4*)&B_lds[bc][bh * 16];
      dst[0] = bv0; dst[1] = bv1;
    } else {
      *(float4*)&B_lds[bc][bh * 8] = bv0;
    }
    *(uint4*)&A_lds[ar][aq * 8] = aval;
    __syncthreads();
    bf16x8 bfr[CT];
#pragma unroll
    for (int ct = 0; ct < CT; ++ct)
      bfr[ct] = *(bf16x8*)&B_lds[w * (CT * 16) + ct * 16 + (l & 15)][(l >> 4) * 8];
#pragma unroll
    for (int t = 0; t < 4; ++t) {
      bf16x8 afr = *(bf16x8*)&A_lds[t * 16 + (l & 15)][(l >> 4) * 8];
#pragma unroll
      for (int ct = 0; ct < CT; ++ct)
        acc[t][ct] = __builtin_amdgcn_mfma_f32_16x16x32_bf16(afr, bfr[ct], acc[t][ct], 0, 0, 0);
    }
  }
#pragma unroll
  for (int t = 0; t < 4; ++t)
#pragma unroll
    for (int ct = 0; ct < CT; ++ct)
#pragma unroll
      for (int i = 0; i < 4; ++i) {
        int row = n0 + t * 16 + (l >> 4) * 4 + i;
        int col = c0 + w * (CT * 16) + ct * 16 + (l & 15);
        float* cp = &C[(size_t)row * N + col];
        float v = acc[t][ct][i];
        if constexpr (EP == 1) v += *cp;
        *cp = v;
      }
}

// ---- LayerNorm over sum of two partial buffers (kan1 split-K reduction fused)
__global__ __launch_bounds__(256) void layernorm_sum_kernel(
    const float* __restrict__ ina, const float* __restrict__ inb,
    const float* __restrict__ g, const float* __restrict__ b, float* __restrict__ out)
{
  __shared__ float pS[4], pQ[4];
  int row = blockIdx.x, tid = threadIdx.x;
  size_t idx = (size_t)row * 256 + tid;
  float v = ina[idx] + inb[idx];
  float s = v, q = v * v;
#pragma unroll
  for (int off = 1; off < 64; off <<= 1) { s += __shfl_xor(s, off); q += __shfl_xor(q, off); }
  if ((tid & 63) == 0) { pS[tid >> 6] = s; pQ[tid >> 6] = q; }
  __syncthreads();
  float S = pS[0] + pS[1] + pS[2] + pS[3];
  float Q = pQ[0] + pQ[1] + pQ[2] + pQ[3];
  float m = S * (1.0f / 256.0f);
  float var = Q * (1.0f / 256.0f) - m * m;
  float rs = rsqrtf(var + 1e-5f);
  out[idx] = (v - m) * rs * g[tid] + b[tid];
}

// ---- RMSNorm
__global__ __launch_bounds__(256) void rmsnorm_kernel(
    const float* __restrict__ in, const float* __restrict__ w, float* __restrict__ out)
{
  __shared__ float p[4];
  int row = blockIdx.x, tid = threadIdx.x;
  float v = in[(size_t)row * 256 + tid];
  float q = v * v;
#pragma unroll
  for (int off = 1; off < 64; off <<= 1) q += __shfl_xor(q, off);
  if ((tid & 63) == 0) p[tid >> 6] = q;
  __syncthreads();
  float s = p[0] + p[1] + p[2] + p[3];
  float rstd = rsqrtf(s * (1.0f / 256.0f) + 1e-5f);
  out[(size_t)row * 256 + tid] = w[tid] * v * rstd;
}

// ---- fp32 GEMM 64x64x16 — kept for N=48 (x_proj)
template<int EP>
__global__ __launch_bounds__(256) void gemm_nt(
    const float* __restrict__ A, const float* __restrict__ W, float* __restrict__ C,
    int M, int N, int K)
{
  __shared__ float As[16][68];
  __shared__ float Wsm[16][68];
  int tid = threadIdx.x;
  int bx = blockIdx.x, by = blockIdx.y;
  int tx = tid & 15, ty = tid >> 4;
  int lr = tid >> 2;
  int lk = (tid & 3) << 2;
  const float* Ap = A + (size_t)(bx * 64 + lr) * K + lk;
  int wrow = by * 64 + lr;
  bool wv = wrow < N;
  const float* Wp = W + (size_t)(wv ? wrow : 0) * K + lk;
  float acc[4][4];
#pragma unroll
  for (int i = 0; i < 4; ++i)
#pragma unroll
    for (int j = 0; j < 4; ++j) acc[i][j] = 0.0f;

#pragma unroll 1
  for (int k0 = 0; k0 < K; k0 += 16) {
    float4 av = *(const float4*)(Ap + k0);
    float4 wvv = wv ? *(const float4*)(Wp + k0) : make_float4(0.f, 0.f, 0.f, 0.f);
    __syncthreads();
    As[lk + 0][lr] = av.x; As[lk + 1][lr] = av.y; As[lk + 2][lr] = av.z; As[lk + 3][lr] = av.w;
    Wsm[lk + 0][lr] = wvv.x; Wsm[lk + 1][lr] = wvv.y; Wsm[lk + 2][lr] = wvv.z; Wsm[lk + 3][lr] = wvv.w;
    __syncthreads();
#pragma unroll
    for (int kk = 0; kk < 16; ++kk) {
      float4 a = *(const float4*)&As[kk][ty * 4];
      float4 b = *(const float4*)&Wsm[kk][tx * 4];
      acc[0][0] += a.x * b.x; acc[0][1] += a.x * b.y; acc[0][2] += a.x * b.z; acc[0][3] += a.x * b.w;
      acc[1][0] += a.y * b.x; acc[1][1] += a.y * b.y; acc[1][2] += a.y * b.z; acc[1][3] += a.y * b.w;
      acc[2][0] += a.z * b.x; acc[2][1] += a.z * b.y; acc[2][2] += a.z * b.z; acc[2][3] += a.z * b.w;
      acc[3][0] += a.w * b.x; acc[3][1] += a.w * b.y; acc[3][2] += a.w * b.z; acc[3][3] += a.w * b.w;
    }
  }
#pragma unroll
  for (int i = 0; i < 4; ++i) {
    int row = bx * 64 + ty * 4 + i;
    int col = by * 64 + tx * 4;
    float* cp = C + (size_t)row * N + col;
    if (col + 3 < N) {
      float4 o;
      if (EP == 1) {
        float4 old = *(const float4*)cp;
        o = make_float4(old.x + acc[i][0], old.y + acc[i][1], old.z + acc[i][2], old.w + acc[i][3]);
      } else {
        o = make_float4(acc[i][0], acc[i][1], acc[i][2], acc[i][3]);
      }
      *(float4*)cp = o;
    } else {
#pragma unroll
      for (int j = 0; j < 4; ++j) if (col + j < N) {
        float v = acc[i][j];
        if (EP == 1) v += cp[j];
        cp[j] = v;
      }
    }
  }
}

// ---- causal depthwise conv (K=4) + bias + SiLU
__global__ __launch_bounds__(256) void conv_silu_kernel(
    const float* __restrict__ proj, const float* __restrict__ cw, const float* __restrict__ cb,
    float* __restrict__ u2)
{
  int idx = blockIdx.x * 256 + threadIdx.x;
  int i = idx & 511;
  int l = (idx >> 9) & 511;
  int bl = idx >> 9;
  const float* p = proj + (size_t)bl * 1024 + i;
  float4 w = *(const float4*)&cw[i * 4];
  float s = cb[i];
  s += (l >= 3) ? p[-3 * 1024] * w.x : 0.0f;
  s += (l >= 2) ? p[-2 * 1024] * w.y : 0.0f;
  s += (l >= 1) ? p[-1 * 1024] * w.z : 0.0f;
  s += p[0] * w.w;
  u2[idx] = siluf(s);
}

// ---- scan pass 1: per-chunk local scan + dA product
__global__ __launch_bounds__(256) void scan_part1_kernel(
    const float* __restrict__ ssm, const float* __restrict__ u2,
    const float* __restrict__ dtw, const float* __restrict__ dtb, const float* __restrict__ alog,
    float* __restrict__ Sg, float* __restrict__ Pg)
{
  const int CL = 64;
  __shared__ float sbuf[CL * 32];
  __shared__ float ubuf[CL][64];
  int tid = threadIdx.x;
  int il = tid >> 2, ns = tid & 3;
  int i0 = blockIdx.x * 64;
  int b = blockIdx.y;
  int lc = blockIdx.z;
  int i = i0 + il;
  float A4[4], wr4[4];
#pragma unroll
  for (int nn = 0; nn < 4; ++nn) {
    A4[nn] = -__expf(alog[i * 16 + ns * 4 + nn]);
    wr4[nn] = dtw[i * 16 + ns * 4 + nn];
  }
  float dtbi = dtb[i];
  size_t rowL = (size_t)b * 512 + lc * CL;

  for (int t = tid; t < CL * 32; t += 256) {
    int r = t >> 5, c = t & 31;
    sbuf[t] = ssm[(rowL + r) * 48 + c];
  }
  for (int t = tid; t < CL * 64; t += 256) {
    int lr = t >> 6, ci = t & 63;
    ubuf[lr][ci] = u2[(rowL + lr) * 512 + i0 + ci];
  }
  __syncthreads();

  float s0 = 0.f, s1 = 0.f, s2 = 0.f, s3 = 0.f;
  float p0 = 1.f, p1 = 1.f, p2 = 1.f, p3 = 1.f;
  for (int ll = 0; ll < CL; ++ll) {
    const float* row = &sbuf[ll * 32];
    float4 dtr = *(const float4*)(row + ns * 4);
    float pdt = dtr.x * wr4[0] + dtr.y * wr4[1] + dtr.z * wr4[2] + dtr.w * wr4[3];
    pdt += __shfl_xor(pdt, 1);
    pdt += __shfl_xor(pdt, 2);
    pdt += dtbi;
    float dtv = (pdt > 20.0f) ? pdt : __logf(1.0f + __expf(pdt));
    float u = ubuf[ll][il];
    float dtu = dtv * u;
    float4 Bv = *(const float4*)(row + 16 + ns * 4);
    float e0 = __expf(dtv * A4[0]);
    float e1 = __expf(dtv * A4[1]);
    float e2 = __expf(dtv * A4[2]);
    float e3 = __expf(dtv * A4[3]);
    s0 = s0 * e0 + dtu * Bv.x;  p0 *= e0;
    s1 = s1 * e1 + dtu * Bv.y;  p1 *= e1;
    s2 = s2 * e2 + dtu * Bv.z;  p2 *= e2;
    s3 = s3 * e3 + dtu * Bv.w;  p3 *= e3;
  }
  size_t off = ((size_t)(b * 8 + lc) * 512 + i) * 16 + ns * 4;
  Sg[off + 0] = s0; Sg[off + 1] = s1; Sg[off + 2] = s2; Sg[off + 3] = s3;
  Pg[off + 0] = p0; Pg[off + 1] = p1; Pg[off + 2] = p2; Pg[off + 3] = p3;
}

// ---- scan pass 2 (combine)
__global__ __launch_bounds__(256) void scan_combine_kernel(
    float* __restrict__ Sg, const float* __restrict__ Pg)
{
  int gid = blockIdx.x * 256 + threadIdx.x;
  int b = gid >> 13;
  int rest = gid & 8191;
  float sin = 0.f;
#pragma unroll
  for (int lc = 0; lc < 8; ++lc) {
    size_t off = (size_t)(b * 8 + lc) * 8192 + rest;
    float S = Sg[off], P = Pg[off];
    Sg[off] = sin;
    sin = sin * P + S;
  }
}

// ---- scan pass 3: recompute from incoming state, fuse y/D/gate
__global__ __launch_bounds__(256) void scan_part2_kernel(
    const float* __restrict__ ssm, float* __restrict__ u2, const float* __restrict__ proj,
    const float* __restrict__ dtw, const float* __restrict__ dtb, const float* __restrict__ alog,
    const float* __restrict__ Dp, const float* __restrict__ Sg)
{
  const int CL = 64;
  __shared__ float sbuf[CL * 48];
  __shared__ float ubuf[CL][64];
  __shared__ float gbuf[CL][64];
  int tid = threadIdx.x;
  int il = tid >> 2, ns = tid & 3;
  int i0 = blockIdx.x * 64;
  int b = blockIdx.y;
  int lc = blockIdx.z;
  int i = i0 + il;
  float A4[4], wr4[4];
#pragma unroll
  for (int nn = 0; nn < 4; ++nn) {
    A4[nn] = -__expf(alog[i * 16 + ns * 4 + nn]);
    wr4[nn] = dtw[i * 16 + ns * 4 + nn];
  }
  float dtbi = dtb[i], Di = Dp[i];
  size_t rowL = (size_t)b * 512 + lc * CL;
  size_t soff = ((size_t)(b * 8 + lc) * 512 + i) * 16 + ns * 4;
  float st0 = Sg[soff + 0], st1 = Sg[soff + 1], st2 = Sg[soff + 2], st3 = Sg[soff + 3];

  for (int t = tid; t < CL * 48; t += 256) {
    sbuf[t] = ssm[rowL * 48 + t];
  }
  for (int t = tid; t < CL * 64; t += 256) {
    int lr = t >> 6, ci = t & 63;
    ubuf[lr][ci] = u2[(rowL + lr) * 512 + i0 + ci];
    gbuf[lr][ci] = proj[(rowL + lr) * 1024 + 512 + i0 + ci];
  }
  __syncthreads();

  for (int ll = 0; ll < CL; ++ll) {
    const float* row = &sbuf[ll * 48];
    float4 dtr = *(const float4*)(row + ns * 4);
    float pdt = dtr.x * wr4[0] + dtr.y * wr4[1] + dtr.z * wr4[2] + dtr.w * wr4[3];
    pdt += __shfl_xor(pdt, 1);
    pdt += __shfl_xor(pdt, 2);
    pdt += dtbi;
    float dtv = (pdt > 20.0f) ? pdt : __logf(1.0f + __expf(pdt));
    float u = ubuf[ll][il];
    float dtu = dtv * u;
    float4 Bv = *(const float4*)(row + 16 + ns * 4);
    float4 Cv = *(const float4*)(row + 32 + ns * 4);
    st0 = st0 * __expf(dtv * A4[0]) + dtu * Bv.x;
    st1 = st1 * __expf(dtv * A4[1]) + dtu * Bv.y;
    st2 = st2 * __expf(dtv * A4[2]) + dtu * Bv.z;
    st3 = st3 * __expf(dtv * A4[3]) + dtu * Bv.w;
    float yp = st0 * Cv.x + st1 * Cv.y + st2 * Cv.z + st3 * Cv.w;
    yp += __shfl_xor(yp, 1);
    yp += __shfl_xor(yp, 2);
    if (ns == 0) {
      float gt = gbuf[ll][il];
      ubuf[ll][il] = (yp + u * Di) * siluf(gt);
    }
  }
  __syncthreads();
  for (int t = tid; t < CL * 64; t += 256) {
    int lr = t >> 6, ci = t & 63;
    u2[(rowL + lr) * 512 + i0 + ci] = ubuf[lr][ci];
  }
}

// ---- mean/max pool
__global__ __launch_bounds__(64) void pool_kernel(const float* __restrict__ hn, float* __restrict__ outp)
{
  int c = blockIdx.x * 64 + threadIdx.x;
  int b = blockIdx.y;
  float s = 0.0f, mx = -3.4e38f;
  for (int l = 0; l < 512; ++l) {
    float v = hn[((size_t)b * 512 + l) * 256 + c];
    s += v;
    mx = fmaxf(mx, v);
  }
  outp[32 + b * 512 + c] = s * (1.0f / 512.0f);
  outp[32 + b * 512 + 256 + c] = mx;
}

// ---- KAN-2 head
__global__ __launch_bounds__(256) void kan2_kernel(
    const float* __restrict__ outp, const float* __restrict__ bw2, const float* __restrict__ sw2,
    const float* __restrict__ ss2, float* __restrict__ logits)
{
  __shared__ float r0[256], r1[256];
  int b = blockIdx.x, tid = threadIdx.x;
  float a0 = 0.0f, a1 = 0.0f;
#pragma unroll
  for (int dd = 0; dd < 2; ++dd) {
    int d = tid + dd * 256;
    float e = outp[32 + b * 512 + d];
    float bb[8];
    bspline8(e, bb);
    float sl = siluf(e);
    {
      float sc = ss2[d];
      const float* sp = &sw2[(size_t)d * 8];
      float t = sl * bw2[d];
      t += (bb[0] * sp[0] + bb[1] * sp[1] + bb[2] * sp[2] + bb[3] * sp[3]
          + bb[4] * sp[4] + bb[5] * sp[5] + bb[6] * sp[6] + bb[7] * sp[7]) * sc;
      a0 += t;
    }
    {
      float sc = ss2[512 + d];
      const float* sp = &sw2[(size_t)(512 + d) * 8];
      float t = sl * bw2[512 + d];
      t += (bb[0] * sp[0] + bb[1] * sp[1] + bb[2] * sp[2] + bb[3] * sp[3]
          + bb[4] * sp[4] + bb[5] * sp[5] + bb[6] * sp[6] + bb[7] * sp[7]) * sc;
      a1 += t;
    }
  }
  r0[tid] = a0; r1[tid] = a1;
  __syncthreads();
  for (int s = 128; s > 0; s >>= 1) {
    if (tid < s) { r0[tid] += r0[tid + s]; r1[tid] += r1[tid + s]; }
    __syncthreads();
  }
  if (tid == 0) { logits[b * 2 + 0] = r0[0]; logits[b * 2 + 1] = r1[0]; }
}

extern "C" void kernel_launch(void* const* d_in, const int* in_sizes, int n_in,
                              void* d_out, int out_size, void* d_ws, size_t ws_size,
                              hipStream_t stream)
{
  const float* x     = (const float*)d_in[0];
  const float* bw1   = (const float*)d_in[1];
  const float* sw1   = (const float*)d_in[2];
  const float* ss1   = (const float*)d_in[3];
  const float* lng   = (const float*)d_in[4];
  const float* lnb   = (const float*)d_in[5];
  const float* normw = (const float*)d_in[6];
  const float* ipw   = (const float*)d_in[7];
  const float* cw    = (const float*)d_in[8];
  const float* cb    = (const float*)d_in[9];
  const float* xpw   = (const float*)d_in[10];
  const float* dtw   = (const float*)d_in[11];
  const float* dtb   = (const float*)d_in[12];
  const float* alog  = (const float*)d_in[13];
  const float* Dp    = (const float*)d_in[14];
  const float* opw   = (const float*)d_in[15];
  const float* nfw   = (const float*)d_in[16];
  const float* bw2   = (const float*)d_in[17];
  const float* sw2   = (const float*)d_in[18];
  const float* ss2   = (const float*)d_in[19];
  float* out = (float*)d_out;

  float* ws   = (float*)d_ws;
  float* h    = ws;                        // 2097152
  float* xn   = h + 2097152;               // 2097152
  float* proj = xn + 2097152;              // 8388608
  float* u2   = proj + 8388608;            // 4194304
  float* ssmb = u2 + 4194304;              // 393216
  ushort* WTu  = (ushort*)(ssmb + 393216);         // 1769472 u16 (884736 fl)
  ushort* ipwB = (ushort*)(ssmb + 393216 + 884736);// 524288 u16 (262144 fl)
  ushort* opwB = ipwB + 524288;                    // 262144 u16 (131072 fl)
  float* xT   = proj;                      // 6291456 fl
  float* xnB  = proj + 6291456;            // 2097152 fl (= proj end exactly)
  float* Sg   = xn;                        // scan-time alias (xn dead)
  float* Pg   = xn + 1048576;
  // total ≈ 73.8 MB (≤ proven 75.8 MB)

  prep_xT_kernel<<<dim3(128, 12), 256, 0, stream>>>(x, xT);
  prep_WT_kernel<<<dim3(27, 256), 256, 0, stream>>>(bw1, sw1, ss1, WTu);
  pack_bf16_kernel<<<2048, 256, 0, stream>>>(ipw, ipwB);   // 2*1024*256
  pack_bf16_kernel<<<1024, 256, 0, stream>>>(opw, opwB);   // 2*256*512
  kan1_mfma_kernel<<<dim3(128, 2, 2), 256, 0, stream>>>(xT, WTu, xn, xnB);
  layernorm_sum_kernel<<<8192, 256, 0, stream>>>(xn, xnB, lng, lnb, h);

  for (int l = 0; l < 2; ++l) {
    rmsnorm_kernel<<<8192, 256, 0, stream>>>(h, normw + l * 256, xn);
    // in_proj (bf16 MFMA): (8192,256)@(1024,256)^T -> proj
    mfma_gemm<2, 0><<<dim3(128, 8), 256, 0, stream>>>(xn, ipwB + (size_t)l * 262144, proj, 1024, 256);
    conv_silu_kernel<<<16384, 256, 0, stream>>>(proj, cw + l * 2048, cb + l * 512, u2);
    gemm_nt<0><<<dim3(128, 1), 256, 0, stream>>>(u2, xpw + (size_t)l * 24576, ssmb, 8192, 48, 512);
    scan_part1_kernel<<<dim3(8, 16, 8), 256, 0, stream>>>(ssmb, u2,
        dtw + l * 8192, dtb + l * 512, alog + l * 8192, Sg, Pg);
    scan_combine_kernel<<<512, 256, 0, stream>>>(Sg, Pg);
    scan_part2_kernel<<<dim3(8, 16, 8), 256, 0, stream>>>(ssmb, u2, proj,
        dtw + l * 8192, dtb + l * 512, alog + l * 8192, Dp + l * 512, Sg);
    // out_proj (bf16 MFMA, +residual): (8192,512)@(256,512)^T += h
    mfma_gemm<1, 1><<<dim3(128, 4), 256, 0, stream>>>(u2, opwB + (size_t)l * 131072, h, 256, 512);
  }

  rmsnorm_kernel<<<8192, 256, 0, stream>>>(h, nfw, xn);
  pool_kernel<<<dim3(4, 16), 64, 0, stream>>>(xn, out);
  kan2_kernel<<<16, 256, 0, stream>>>(out, bw2, sw2, ss2, out);
}